// Round 9
// baseline (820.637 us; speedup 1.0000x reference)
//
#include <hip/hip_runtime.h>
#include <hip/hip_bf16.h>
#include <hip/hip_fp16.h>

typedef _Float16 half8 __attribute__((ext_vector_type(8)));
typedef float floatx4 __attribute__((ext_vector_type(4)));

__device__ __forceinline__ float siluf(float x) {
    return x / (1.0f + __expf(-x));
}

// ---------------- species per node + histogram ----------------
__global__ void k_species(const float* __restrict__ attrs, int* __restrict__ species_o,
                          int* __restrict__ zcount, int N) {
    int n = blockIdx.x * 256 + threadIdx.x;
    if (n >= N) return;
    int z = 0;
    #pragma unroll
    for (int k = 1; k < 10; k++) if (attrs[n * 10 + k] > 0.5f) z = k;
    species_o[n] = z;
    atomicAdd(&zcount[z], 1);
}

__global__ void k_zscan(const int* __restrict__ zcount, int* __restrict__ zcur) {
    if (threadIdx.x == 0) {
        int run = 0;
        for (int z = 0; z < 10; z++) { zcur[z] = run; run += zcount[z]; }
    }
}

__global__ void k_zperm(const int* __restrict__ species_o, int* __restrict__ zcur,
                        int* __restrict__ perm_n, int* __restrict__ inv_n, int N) {
    int n = blockIdx.x * 256 + threadIdx.x;
    if (n >= N) return;
    int pos = atomicAdd(&zcur[species_o[n]], 1);
    perm_n[pos] = n;
    inv_n[n] = pos;
}

// ---------------- init state in SPECIES-SORTED node order ----------------
__global__ void k_init(const int* __restrict__ perm_n, const int* __restrict__ species_o,
                       const float* __restrict__ Wemb, int* __restrict__ species_s,
                       int* __restrict__ origid, float* __restrict__ s,
                       float* __restrict__ v, int N) {
    int p = blockIdx.x * 4 + (threadIdx.x >> 6);
    if (p >= N) return;
    int lane = threadIdx.x & 63;
    int n = perm_n[p];
    int z = species_o[n];
    if (lane == 0) { species_s[p] = z; origid[p] = n; }
    s[(size_t)p * 64 + lane] = Wemb[z * 64 + lane];
    v[(size_t)p * 192 + lane] = 0.0f;
    v[(size_t)p * 192 + 64 + lane] = 0.0f;
    v[(size_t)p * 192 + 128 + lane] = 0.0f;
}

// ---------------- counting sort of edges by (sorted) receiver ----------------
__global__ void k_hist(const int* __restrict__ ei, const int* __restrict__ inv_n,
                       int* __restrict__ deg, int E) {
    int e = blockIdx.x * 256 + threadIdx.x;
    if (e < E) atomicAdd(&deg[inv_n[ei[E + e]]], 1);
}

__global__ void k_scan(const int* __restrict__ deg, int* __restrict__ rowptr,
                       int* __restrict__ cursor, int N) {
    __shared__ int part[1024];
    int t = threadIdx.x;
    int chunk = (N + 1023) / 1024;
    int lo = t * chunk, hi = min(lo + chunk, N);
    int sum = 0;
    for (int i = lo; i < hi; i++) sum += deg[i];
    part[t] = sum;
    __syncthreads();
    for (int off = 1; off < 1024; off <<= 1) {
        int add = (t >= off) ? part[t - off] : 0;
        __syncthreads();
        part[t] += add;
        __syncthreads();
    }
    int run = (t > 0) ? part[t - 1] : 0;
    for (int i = lo; i < hi; i++) { rowptr[i] = run; cursor[i] = run; run += deg[i]; }
    if (t == 1023) rowptr[N] = part[1023];
}

__global__ void k_eperm(const int* __restrict__ ei, const int* __restrict__ inv_n,
                        int* __restrict__ cursor, int* __restrict__ perm, int E) {
    int e = blockIdx.x * 256 + threadIdx.x;
    if (e < E) {
        int r = inv_n[ei[E + e]];
        int pos = atomicAdd(&cursor[r], 1);
        perm[pos] = e;
    }
}

// ---------------- geometry + radial basis on SORTED edge order ----------------
__global__ void k_geom(const int* __restrict__ ei, const int* __restrict__ perm,
                       const int* __restrict__ inv_n, const float* __restrict__ pos,
                       const float* __restrict__ shifts, float4* __restrict__ geo,
                       _Float16* __restrict__ efT, int* __restrict__ snd_s,
                       int* __restrict__ rcv_s, int E) {
    int j = blockIdx.x * 64 + threadIdx.x;
    if (j >= E) return;
    int e = perm[j];
    int snd = ei[e], rcv = ei[E + e];
    float dx = pos[rcv * 3 + 0] - pos[snd * 3 + 0] + shifts[e * 3 + 0];
    float dy = pos[rcv * 3 + 1] - pos[snd * 3 + 1] + shifts[e * 3 + 1];
    float dz = pos[rcv * 3 + 2] - pos[snd * 3 + 2] + shifts[e * 3 + 2];
    float r = sqrtf(dx * dx + dy * dy + dz * dz);
    float rin = 1.0f / (r + 1e-9f);
    const float SQ3 = 1.7320508075688772f;
    geo[j] = make_float4(SQ3 * dx * rin, SQ3 * dy * rin, SQ3 * dz * rin, 0.0f);
    snd_s[j] = inv_n[snd];
    rcv_s[j] = inv_n[rcv];
    float u = r * 0.2f;
    float env = 0.0f;
    if (u < 1.0f) {
        float u2 = u * u;
        float u6 = u2 * u2 * u2;
        env = 1.0f - 28.0f * u6 + 48.0f * u6 * u - 21.0f * u6 * u2;
    }
    const float PIF = 3.14159265358979f;
    float x = PIF * u;
    float sp = __sinf(x), cp = __cosf(x);
    float coef = 0.6324555320336759f * rin * env;
    float sm1 = 0.0f, scur = sp, twoc = 2.0f * cp;
    #pragma unroll
    for (int k = 0; k < 8; k++) {
        efT[k * (size_t)E + j] = (_Float16)(coef * scur);
        float nxt = twoc * scur - sm1;
        sm1 = scur; scur = nxt;
    }
}

// -------- weight prep (edge MLP): RW1/RW2/RW3 -> fp16 B-frag (16x16x32 MFMA) --------
__global__ void k_wprep(const float* __restrict__ RW1, const float* __restrict__ RW2,
                        const float* __restrict__ RW3, _Float16* __restrict__ B1f,
                        _Float16* __restrict__ B2f, _Float16* __restrict__ B3f) {
    int lane = threadIdx.x;
    int t = blockIdx.x;
    int layer = t / 52;
    int tt = t % 52;
    int quad = lane >> 4, colx = lane & 15;
    if (tt < 4) {
        int nt = tt;
        const float* W = RW1 + (size_t)layer * 512;
        _Float16* dst = B1f + (size_t)layer * 2048 + ((size_t)nt * 64 + lane) * 8;
        #pragma unroll
        for (int j = 0; j < 8; j++) {
            int k = quad * 8 + j, n = nt * 16 + colx;
            dst[j] = (k < 8) ? (_Float16)W[k * 64 + n] : (_Float16)0.0f;
        }
    } else if (tt < 12) {
        int u = tt - 4;
        int kt = u >> 2, nt = u & 3;
        const float* W = RW2 + (size_t)layer * 4096;
        _Float16* dst = B2f + (size_t)layer * 4096 + (((size_t)kt * 4 + nt) * 64 + lane) * 8;
        #pragma unroll
        for (int j = 0; j < 8; j++) {
            int k = kt * 32 + quad * 8 + j, n = nt * 16 + colx;
            dst[j] = (_Float16)W[k * 64 + n];
        }
    } else {
        int u = tt - 12;
        int kt = u / 20, nt = u % 20;
        const float* W = RW3 + (size_t)layer * 20480;
        _Float16* dst = B3f + (size_t)layer * 20480 + (((size_t)kt * 20 + nt) * 64 + lane) * 8;
        #pragma unroll
        for (int j = 0; j < 8; j++) {
            int k = kt * 32 + quad * 8 + j, n = nt * 16 + colx;
            dst[j] = (_Float16)W[k * 320 + n];
        }
    }
}

// -------- weight prep (node mats): 64x64 fp32 -> B-frag fp16. 26 mats per layer -----
__global__ void k_wprep_node(const float* __restrict__ Wup_s, const float* __restrict__ Wup_v,
                             const float* __restrict__ Wout_s, const float* __restrict__ Wout_v,
                             const float* __restrict__ Wprod_s, const float* __restrict__ Wprod_v,
                             const float* __restrict__ Wsc_s, const float* __restrict__ Wsc_v,
                             _Float16* __restrict__ Bmats) {
    int mid = blockIdx.x;
    int layer = mid / 26, m = mid % 26;
    const float* src;
    if (m == 0)      src = Wup_s  + (size_t)layer * 4096;
    else if (m == 1) src = Wup_v  + (size_t)layer * 4096;
    else if (m == 2) src = Wout_s + (size_t)layer * 4096;
    else if (m == 3) src = Wout_v + (size_t)layer * 4096;
    else if (m == 4) src = Wprod_s + (size_t)layer * 4096;
    else if (m == 5) src = Wprod_v + (size_t)layer * 4096;
    else if (m < 16) src = Wsc_s + (size_t)layer * 40960 + (size_t)(m - 6) * 4096;
    else             src = Wsc_v + (size_t)layer * 40960 + (size_t)(m - 16) * 4096;
    _Float16* dst = Bmats + (size_t)mid * 4096;
    int lane = threadIdx.x, quad = lane >> 4, colx = lane & 15;
    for (int t = 0; t < 8; t++) {
        int kt = t >> 2, nt = t & 3;
        #pragma unroll
        for (int j = 0; j < 8; j++) {
            int k = kt * 32 + quad * 8 + j, n = nt * 16 + colx;
            dst[(size_t)t * 512 + lane * 8 + j] = (_Float16)src[k * 64 + n];
        }
    }
}

// helper: load A-frag (8 ch of one node) from planar fp32, fp16-convert
__device__ __forceinline__ half8 loadA(const float* __restrict__ base, bool valid) {
    half8 a;
    if (valid) {
        float4 f0 = ((const float4*)base)[0];
        float4 f1 = ((const float4*)base)[1];
        a[0]=(_Float16)f0.x; a[1]=(_Float16)f0.y; a[2]=(_Float16)f0.z; a[3]=(_Float16)f0.w;
        a[4]=(_Float16)f1.x; a[5]=(_Float16)f1.y; a[6]=(_Float16)f1.z; a[7]=(_Float16)f1.w;
    } else {
        #pragma unroll
        for (int j = 0; j < 8; j++) a[j] = (_Float16)0.0f;
    }
    return a;
}

// ---- node kernel A: up-projection (fp16 pack) + species skip (scp) + agg zero-init --
__global__ __launch_bounds__(256, 4)
void k_nodeA(const float* __restrict__ s, const float* __restrict__ v,
             const int* __restrict__ species,
             const _Float16* __restrict__ Bup_s, const _Float16* __restrict__ Bup_v,
             const _Float16* __restrict__ Bsc_s, const _Float16* __restrict__ Bsc_v,
             const float* __restrict__ Wsc_s32, const float* __restrict__ Wsc_v32,
             float2* __restrict__ packh, float4* __restrict__ scp,
             float* __restrict__ agg0, float* __restrict__ agg1, int N) {
    const int tid = threadIdx.x;
    const int lane = tid & 63, wave = tid >> 6;
    const int quad = lane >> 4, col = lane & 15;
    const int n0 = blockIdx.x * 64 + wave * 16;
    if (n0 >= N) return;   // no barriers in this kernel

    half8 as[2], av0[2], av1[2], av2[2];
    int node = n0 + col;
    bool vn = node < N;
    const float* sp = s + (size_t)(vn ? node : 0) * 64;
    const float* vp = v + (size_t)(vn ? node : 0) * 192;
    #pragma unroll
    for (int kt = 0; kt < 2; kt++) {
        int kb = kt * 32 + quad * 8;
        as[kt]  = loadA(sp + kb, vn);
        av0[kt] = loadA(vp + kb, vn);
        av1[kt] = loadA(vp + 64 + kb, vn);
        av2[kt] = loadA(vp + 128 + kb, vn);
    }

    // up-projection -> fp16 pack; also zero agg for this layer
    #pragma unroll
    for (int nt = 0; nt < 4; nt++) {
        floatx4 cs = {0,0,0,0}, c0 = {0,0,0,0}, c1 = {0,0,0,0}, c2 = {0,0,0,0};
        #pragma unroll
        for (int kt = 0; kt < 2; kt++) {
            half8 bs = *(const half8*)(Bup_s + (((size_t)kt * 4 + nt) * 64 + lane) * 8);
            half8 bv = *(const half8*)(Bup_v + (((size_t)kt * 4 + nt) * 64 + lane) * 8);
            cs = __builtin_amdgcn_mfma_f32_16x16x32_f16(as[kt],  bs, cs, 0, 0, 0);
            c0 = __builtin_amdgcn_mfma_f32_16x16x32_f16(av0[kt], bv, c0, 0, 0, 0);
            c1 = __builtin_amdgcn_mfma_f32_16x16x32_f16(av1[kt], bv, c1, 0, 0, 0);
            c2 = __builtin_amdgcn_mfma_f32_16x16x32_f16(av2[kt], bv, c2, 0, 0, 0);
        }
        int ch = nt * 16 + col;
        #pragma unroll
        for (int r = 0; r < 4; r++) {
            int n = n0 + quad * 4 + r;
            if (n < N) {
                union { __half2 h; float f; } u1, u2;
                u1.h = __floats2half2_rn(cs[r], c0[r]);
                u2.h = __floats2half2_rn(c1[r], c2[r]);
                packh[(size_t)n * 64 + ch] = make_float2(u1.f, u2.f);
                agg0[(size_t)n * 64 + ch] = 0.0f;
                agg1[(size_t)n * 192 + ch] = 0.0f;
                agg1[(size_t)n * 192 + 64 + ch] = 0.0f;
                agg1[(size_t)n * 192 + 128 + ch] = 0.0f;
            }
        }
    }

    // species skip connection -> scp
    int zlo = species[n0];
    int zhi = species[min(n0 + 15, N - 1)];
    if (zlo == zhi) {
        const _Float16* Bs = Bsc_s + (size_t)zlo * 4096;
        const _Float16* Bv = Bsc_v + (size_t)zlo * 4096;
        #pragma unroll
        for (int nt = 0; nt < 4; nt++) {
            floatx4 cs = {0,0,0,0}, c0 = {0,0,0,0}, c1 = {0,0,0,0}, c2 = {0,0,0,0};
            #pragma unroll
            for (int kt = 0; kt < 2; kt++) {
                half8 bs = *(const half8*)(Bs + (((size_t)kt * 4 + nt) * 64 + lane) * 8);
                half8 bv = *(const half8*)(Bv + (((size_t)kt * 4 + nt) * 64 + lane) * 8);
                cs = __builtin_amdgcn_mfma_f32_16x16x32_f16(as[kt],  bs, cs, 0, 0, 0);
                c0 = __builtin_amdgcn_mfma_f32_16x16x32_f16(av0[kt], bv, c0, 0, 0, 0);
                c1 = __builtin_amdgcn_mfma_f32_16x16x32_f16(av1[kt], bv, c1, 0, 0, 0);
                c2 = __builtin_amdgcn_mfma_f32_16x16x32_f16(av2[kt], bv, c2, 0, 0, 0);
            }
            #pragma unroll
            for (int r = 0; r < 4; r++) {
                int n = n0 + quad * 4 + r;
                if (n < N)
                    scp[(size_t)n * 64 + nt * 16 + col] = make_float4(cs[r], c0[r], c1[r], c2[r]);
            }
        }
    } else {
        for (int m = 0; m < 16; m++) {
            int n = n0 + m;
            if (n >= N) break;
            int z = species[n];
            const float* Ws = Wsc_s32 + (size_t)z * 4096;
            const float* Wv = Wsc_v32 + (size_t)z * 4096;
            float sv = s[(size_t)n * 64 + lane];
            float w0 = v[(size_t)n * 192 + lane];
            float w1 = v[(size_t)n * 192 + 64 + lane];
            float w2 = v[(size_t)n * 192 + 128 + lane];
            float a = 0, b0 = 0, b1 = 0, b2 = 0;
            for (int c = 0; c < 64; c++) {
                float ws = Ws[c * 64 + lane], wv = Wv[c * 64 + lane];
                a  = fmaf(__shfl(sv, c), ws, a);
                b0 = fmaf(__shfl(w0, c), wv, b0);
                b1 = fmaf(__shfl(w1, c), wv, b1);
                b2 = fmaf(__shfl(w2, c), wv, b2);
            }
            scp[(size_t)n * 64 + lane] = make_float4(a, b0, b1, b2);
        }
    }
}

// ---- message kernel: MFMA edge-MLP + FUSED run-compressed atomic aggregation ----
// Edges sorted by receiver; wave = 16 consecutive edges. After the RW3 MFMAs the
// 16x16 message tile goes through per-wave LDS; quad-0 lanes run-scan the 16 sorted
// edges per channel and atomicAdd once per (run, channel) into agg0/agg1.
#define ROWP 72
__global__ __launch_bounds__(256, 4)
void k_msg(const _Float16* __restrict__ efT, const float4* __restrict__ geo,
           const int* __restrict__ snd_s, const int* __restrict__ rcv_s,
           const float2* __restrict__ packh,
           const _Float16* __restrict__ B1f, const _Float16* __restrict__ B2f,
           const _Float16* __restrict__ B3f,
           float* __restrict__ agg0, float* __restrict__ agg1, int E) {
    __shared__ float4 shraw[1152];               // 18432 B: a2|a3, later reused as red
    _Float16* a2 = (_Float16*)shraw;             // 9216 B
    _Float16* a3 = (_Float16*)shraw + 4608;      // 9216 B
    float4* red = shraw;                         // 4 waves * 256 float4 = 16384 B
    const int tid = threadIdx.x;
    const int lane = tid & 63;
    const int wave = tid >> 6;
    const int quad = lane >> 4;
    const int col = lane & 15;
    const int j0 = blockIdx.x * 64 + wave * 16;

    _Float16* a2w = a2 + wave * 16 * ROWP;
    _Float16* a3w = a3 + wave * 16 * ROWP;

    // ---- stage 1: h1 = silu(ef @ RW1) (K padded 8->32) ----
    half8 aef;
    #pragma unroll
    for (int k = 0; k < 8; k++) aef[k] = (_Float16)0.0f;
    if (quad == 0) {
        int je = j0 + col;
        if (je < E) {
            #pragma unroll
            for (int k = 0; k < 8; k++) aef[k] = efT[(size_t)k * E + je];
        }
    }
    {
        floatx4 c1[4];
        #pragma unroll
        for (int nt = 0; nt < 4; nt++) {
            c1[nt] = (floatx4){0.0f, 0.0f, 0.0f, 0.0f};
            half8 b = *(const half8*)(B1f + ((size_t)nt * 64 + lane) * 8);
            c1[nt] = __builtin_amdgcn_mfma_f32_16x16x32_f16(aef, b, c1[nt], 0, 0, 0);
        }
        #pragma unroll
        for (int nt = 0; nt < 4; nt++)
            #pragma unroll
            for (int r = 0; r < 4; r++)
                a2w[(quad * 4 + r) * ROWP + nt * 16 + col] = (_Float16)siluf(c1[nt][r]);
    }
    __syncthreads();

    // ---- stage 2: h2 = silu(h1 @ RW2) ----
    {
        half8 af0 = *(const half8*)&a2w[col * ROWP + quad * 8];
        half8 af1 = *(const half8*)&a2w[col * ROWP + 32 + quad * 8];
        floatx4 c2[4];
        #pragma unroll
        for (int nt = 0; nt < 4; nt++) {
            c2[nt] = (floatx4){0.0f, 0.0f, 0.0f, 0.0f};
            half8 b0 = *(const half8*)(B2f + (((size_t)0 * 4 + nt) * 64 + lane) * 8);
            half8 b1 = *(const half8*)(B2f + (((size_t)1 * 4 + nt) * 64 + lane) * 8);
            c2[nt] = __builtin_amdgcn_mfma_f32_16x16x32_f16(af0, b0, c2[nt], 0, 0, 0);
            c2[nt] = __builtin_amdgcn_mfma_f32_16x16x32_f16(af1, b1, c2[nt], 0, 0, 0);
        }
        #pragma unroll
        for (int nt = 0; nt < 4; nt++)
            #pragma unroll
            for (int r = 0; r < 4; r++)
                a3w[(quad * 4 + r) * ROWP + nt * 16 + col] = (_Float16)siluf(c2[nt][r]);
    }
    __syncthreads();

    const float inv32 = 1.0f / 32.0f;
    const float is3 = 0.5773502691896258f;
    const float is2 = 0.7071067811865476f;
    half8 a3f0 = *(const half8*)&a3w[col * ROWP + quad * 8];
    half8 a3f1 = *(const half8*)&a3w[col * ROWP + 32 + quad * 8];
    __syncthreads();   // a3 regs loaded in ALL waves before red overlays the buffer

    float4* redw = red + wave * 256;

    for (int cb = 0; cb < 4; cb++) {
        floatx4 acc[5];
        #pragma unroll
        for (int q = 0; q < 5; q++) {
            acc[q] = (floatx4){0.0f, 0.0f, 0.0f, 0.0f};
            int nt = q * 4 + cb;
            half8 b0 = *(const half8*)(B3f + (((size_t)0 * 20 + nt) * 64 + lane) * 8);
            half8 b1 = *(const half8*)(B3f + (((size_t)1 * 20 + nt) * 64 + lane) * 8);
            acc[q] = __builtin_amdgcn_mfma_f32_16x16x32_f16(a3f0, b0, acc[q], 0, 0, 0);
            acc[q] = __builtin_amdgcn_mfma_f32_16x16x32_f16(a3f1, b1, acc[q], 0, 0, 0);
        }
        const int c = cb * 16 + col;
        #pragma unroll
        for (int r = 0; r < 4; r++) {
            int m = quad * 4 + r;
            int jj = j0 + m;
            float4 mval = make_float4(0.0f, 0.0f, 0.0f, 0.0f);
            if (jj < E) {
                int snd = snd_s[jj];
                float4 g = geo[jj];
                float2 pp = packh[(size_t)snd * 64 + c];
                union { float f; __half2 h; } ua, ub;
                ua.f = pp.x; ub.f = pp.y;
                float2 f1 = __half22float2(ua.h);   // (s_up, v0)
                float2 f2 = __half22float2(ub.h);   // (v1, v2)
                float pvx = f1.x, pvy = f1.y, pvz = f2.x, pvw = f2.y;
                float w00 = acc[0][r], w110 = acc[1][r], w011 = acc[2][r];
                float w101 = acc[3][r], w111 = acc[4][r];
                float dvy = pvy * g.x + pvz * g.y + pvw * g.z;
                float m0 = (w00 * pvx + w110 * dvy * is3) * inv32;
                float cxv = pvz * g.z - pvw * g.y;
                float cyv = pvw * g.x - pvy * g.z;
                float czv = pvy * g.y - pvz * g.x;
                mval.x = m0;
                mval.y = (w011 * pvx * g.x + w101 * pvy + w111 * cxv * is2) * inv32;
                mval.z = (w011 * pvx * g.y + w101 * pvz + w111 * cyv * is2) * inv32;
                mval.w = (w011 * pvx * g.z + w101 * pvw + w111 * czv * is2) * inv32;
            }
            redw[m * 16 + col] = mval;
        }
        __syncthreads();
        if (quad == 0) {
            // run-scan 16 sorted edges for channel c; one atomic set per run
            float4 a = make_float4(0.0f, 0.0f, 0.0f, 0.0f);
            int prev = -1;
            for (int m = 0; m < 16; m++) {
                int jj = j0 + m;
                if (jj >= E) break;
                int rr = rcv_s[jj];
                float4 mv = redw[m * 16 + col];
                if (rr != prev) {
                    if (prev >= 0) {
                        atomicAdd(&agg0[(size_t)prev * 64 + c], a.x);
                        atomicAdd(&agg1[(size_t)prev * 192 + c], a.y);
                        atomicAdd(&agg1[(size_t)prev * 192 + 64 + c], a.z);
                        atomicAdd(&agg1[(size_t)prev * 192 + 128 + c], a.w);
                    }
                    a = mv; prev = rr;
                } else {
                    a.x += mv.x; a.y += mv.y; a.z += mv.z; a.w += mv.w;
                }
            }
            if (prev >= 0) {
                atomicAdd(&agg0[(size_t)prev * 64 + c], a.x);
                atomicAdd(&agg1[(size_t)prev * 192 + c], a.y);
                atomicAdd(&agg1[(size_t)prev * 192 + 64 + c], a.z);
                atomicAdd(&agg1[(size_t)prev * 192 + 128 + c], a.w);
            }
        }
        __syncthreads();
    }
}

// ---- node kernel B: Wout MFMA -> P0/P1 epilogue -> LDS transpose -> Wprod MFMA -----
#define ROWPB 72
__global__ __launch_bounds__(256, 4)
void k_nodeB(const float* __restrict__ agg0, const float* __restrict__ agg1,
             const int* __restrict__ species, const int* __restrict__ origid,
             const _Float16* __restrict__ Bout_s, const _Float16* __restrict__ Bout_v,
             const _Float16* __restrict__ Bprod_s, const _Float16* __restrict__ Bprod_v,
             const float* __restrict__ P0l, const float* __restrict__ P1l,
             const float4* __restrict__ scp, float* __restrict__ s,
             float* __restrict__ v, float* __restrict__ out,
             int N, int layer, int Ltot) {
    __shared__ _Float16 lds[4 * 4 * 16 * ROWPB];
    const int tid = threadIdx.x;
    const int lane = tid & 63, wave = tid >> 6;
    const int quad = lane >> 4, col = lane & 15;
    const int n0 = blockIdx.x * 64 + wave * 16;
    const bool act = n0 < N;
    _Float16* lw = lds + wave * 4 * 16 * ROWPB;

    if (act) {
        half8 as[2], av0[2], av1[2], av2[2];
        int node = n0 + col;
        bool vn = node < N;
        const float* ap = agg0 + (size_t)(vn ? node : 0) * 64;
        const float* vp = agg1 + (size_t)(vn ? node : 0) * 192;
        #pragma unroll
        for (int kt = 0; kt < 2; kt++) {
            int kb = kt * 32 + quad * 8;
            as[kt]  = loadA(ap + kb, vn);
            av0[kt] = loadA(vp + kb, vn);
            av1[kt] = loadA(vp + 64 + kb, vn);
            av2[kt] = loadA(vp + 128 + kb, vn);
        }
        #pragma unroll
        for (int nt = 0; nt < 4; nt++) {
            floatx4 cs = {0,0,0,0}, c0 = {0,0,0,0}, c1 = {0,0,0,0}, c2 = {0,0,0,0};
            #pragma unroll
            for (int kt = 0; kt < 2; kt++) {
                half8 bs = *(const half8*)(Bout_s + (((size_t)kt * 4 + nt) * 64 + lane) * 8);
                half8 bv = *(const half8*)(Bout_v + (((size_t)kt * 4 + nt) * 64 + lane) * 8);
                cs = __builtin_amdgcn_mfma_f32_16x16x32_f16(as[kt],  bs, cs, 0, 0, 0);
                c0 = __builtin_amdgcn_mfma_f32_16x16x32_f16(av0[kt], bv, c0, 0, 0, 0);
                c1 = __builtin_amdgcn_mfma_f32_16x16x32_f16(av1[kt], bv, c1, 0, 0, 0);
                c2 = __builtin_amdgcn_mfma_f32_16x16x32_f16(av2[kt], bv, c2, 0, 0, 0);
            }
            int ch = nt * 16 + col;
            #pragma unroll
            for (int r = 0; r < 4; r++) {
                int nl = quad * 4 + r;
                int n = n0 + nl;
                float ps = 0.0f, p0v = 0.0f, p1v = 0.0f, p2v = 0.0f;
                if (n < N) {
                    int z = species[n];
                    const float* p = P0l + ((size_t)z * 64 + ch) * 3;
                    const float* q = P1l + ((size_t)z * 64 + ch) * 2;
                    float msv = cs[r];
                    float m0 = c0[r], m1 = c1[r], m2 = c2[r];
                    ps = p[0] * msv + p[1] * msv * msv + p[2] * (m0 * m0 + m1 * m1 + m2 * m2);
                    float qq = q[0] + q[1] * msv;
                    p0v = qq * m0; p1v = qq * m1; p2v = qq * m2;
                }
                lw[0 * 16 * ROWPB + nl * ROWPB + ch] = (_Float16)ps;
                lw[1 * 16 * ROWPB + nl * ROWPB + ch] = (_Float16)p0v;
                lw[2 * 16 * ROWPB + nl * ROWPB + ch] = (_Float16)p1v;
                lw[3 * 16 * ROWPB + nl * ROWPB + ch] = (_Float16)p2v;
            }
        }
    }
    __syncthreads();
    if (act) {
        half8 as[2], av0[2], av1[2], av2[2];
        #pragma unroll
        for (int kt = 0; kt < 2; kt++) {
            int kb = kt * 32 + quad * 8;
            as[kt]  = *(const half8*)&lw[0 * 16 * ROWPB + col * ROWPB + kb];
            av0[kt] = *(const half8*)&lw[1 * 16 * ROWPB + col * ROWPB + kb];
            av1[kt] = *(const half8*)&lw[2 * 16 * ROWPB + col * ROWPB + kb];
            av2[kt] = *(const half8*)&lw[3 * 16 * ROWPB + col * ROWPB + kb];
        }
        #pragma unroll
        for (int nt = 0; nt < 4; nt++) {
            floatx4 cs = {0,0,0,0}, c0 = {0,0,0,0}, c1 = {0,0,0,0}, c2 = {0,0,0,0};
            #pragma unroll
            for (int kt = 0; kt < 2; kt++) {
                half8 bs = *(const half8*)(Bprod_s + (((size_t)kt * 4 + nt) * 64 + lane) * 8);
                half8 bv = *(const half8*)(Bprod_v + (((size_t)kt * 4 + nt) * 64 + lane) * 8);
                cs = __builtin_amdgcn_mfma_f32_16x16x32_f16(as[kt],  bs, cs, 0, 0, 0);
                c0 = __builtin_amdgcn_mfma_f32_16x16x32_f16(av0[kt], bv, c0, 0, 0, 0);
                c1 = __builtin_amdgcn_mfma_f32_16x16x32_f16(av1[kt], bv, c1, 0, 0, 0);
                c2 = __builtin_amdgcn_mfma_f32_16x16x32_f16(av2[kt], bv, c2, 0, 0, 0);
            }
            int ch = nt * 16 + col;
            #pragma unroll
            for (int r = 0; r < 4; r++) {
                int n = n0 + quad * 4 + r;
                if (n < N) {
                    float4 sc = scp[(size_t)n * 64 + ch];
                    float sval = cs[r] + sc.x;
                    s[(size_t)n * 64 + ch] = sval;
                    v[(size_t)n * 192 + ch] = c0[r] + sc.y;
                    v[(size_t)n * 192 + 64 + ch] = c1[r] + sc.z;
                    v[(size_t)n * 192 + 128 + ch] = c2[r] + sc.w;
                    out[(size_t)origid[n] * (Ltot * 64) + layer * 64 + ch] = sval;
                }
            }
        }
    }
}

extern "C" void kernel_launch(void* const* d_in, const int* in_sizes, int n_in,
                              void* d_out, int out_size, void* d_ws, size_t ws_size,
                              hipStream_t stream) {
    const float* node_attrs = (const float*)d_in[0];
    const float* atom_pos   = (const float*)d_in[1];
    const float* shifts     = (const float*)d_in[2];
    const float* W_embed    = (const float*)d_in[3];
    const float* Wup_s      = (const float*)d_in[4];
    const float* Wup_v      = (const float*)d_in[5];
    const float* RW1        = (const float*)d_in[6];
    const float* RW2        = (const float*)d_in[7];
    const float* RW3        = (const float*)d_in[8];
    const float* Wout_s     = (const float*)d_in[9];
    const float* Wout_v     = (const float*)d_in[10];
    const float* Wsc_s      = (const float*)d_in[11];
    const float* Wsc_v      = (const float*)d_in[12];
    const float* P0         = (const float*)d_in[13];
    const float* P1         = (const float*)d_in[14];
    const float* Wprod_s    = (const float*)d_in[15];
    const float* Wprod_v    = (const float*)d_in[16];
    const int*   ei         = (const int*)d_in[17];

    const int N = in_sizes[0] / 10;
    const int E = in_sizes[17] / 2;
    const int L = in_sizes[4] / 4096;
    float* out = (float*)d_out;

    char* wsb = (char*)d_ws;
    size_t off = 0;
    auto alloci = [&](size_t n) {
        int* p = (int*)(wsb + off);
        off = (off + n * 4 + 255) / 256 * 256;
        return p;
    };
    auto allocf = [&](size_t n) {
        float* p = (float*)(wsb + off);
        off = (off + n * 4 + 255) / 256 * 256;
        return p;
    };
    auto alloch = [&](size_t n) {
        _Float16* p = (_Float16*)(wsb + off);
        off = (off + n * 2 + 255) / 256 * 256;
        return p;
    };
    int* species_o = alloci(N);
    int* species_s = alloci(N);
    int* zcount    = alloci(16);
    int* zcur      = alloci(16);
    int* perm_n    = alloci(N);
    int* inv_n     = alloci(N);
    int* origid    = alloci(N);
    int* deg       = alloci(N);
    int* rowptr    = alloci(N + 1);
    int* cursor    = alloci(N);
    int* perm      = alloci(E);
    int* snd_s     = alloci(E);
    int* rcv_s     = alloci(E);
    float* s     = allocf((size_t)N * 64);
    float* v     = allocf((size_t)N * 192);
    float* agg0  = allocf((size_t)N * 64);
    float* agg1  = allocf((size_t)N * 192);
    float* geo   = allocf((size_t)E * 4);
    _Float16* efT = alloch((size_t)E * 8);
    float* packh = allocf((size_t)N * 128);    // fp16 half4 per (node, ch) = float2
    float* scp   = allocf((size_t)N * 256);
    _Float16* B1f   = alloch((size_t)L * 2048);
    _Float16* B2f   = alloch((size_t)L * 4096);
    _Float16* B3f   = alloch((size_t)L * 20480);
    _Float16* Bmats = alloch((size_t)L * 26 * 4096);
    (void)n_in; (void)out_size; (void)ws_size;

    const int NT = (N + 63) / 64;
    const int NB = (N + 255) / 256;
    const int ET = (E + 63) / 64;
    const int EB = (E + 255) / 256;

    hipMemsetAsync(zcount, 0, 16 * sizeof(int), stream);
    hipMemsetAsync(deg, 0, (size_t)N * sizeof(int), stream);
    k_species<<<NB, 256, 0, stream>>>(node_attrs, species_o, zcount, N);
    k_zscan<<<1, 64, 0, stream>>>(zcount, zcur);
    k_zperm<<<NB, 256, 0, stream>>>(species_o, zcur, perm_n, inv_n, N);
    k_init<<<(N + 3) / 4, 256, 0, stream>>>(perm_n, species_o, W_embed, species_s,
                                            origid, s, v, N);
    k_hist<<<EB, 256, 0, stream>>>(ei, inv_n, deg, E);
    k_scan<<<1, 1024, 0, stream>>>(deg, rowptr, cursor, N);
    k_eperm<<<EB, 256, 0, stream>>>(ei, inv_n, cursor, perm, E);
    k_geom<<<ET, 64, 0, stream>>>(ei, perm, inv_n, atom_pos, shifts,
                                  (float4*)geo, efT, snd_s, rcv_s, E);
    k_wprep<<<52 * L, 64, 0, stream>>>(RW1, RW2, RW3, B1f, B2f, B3f);
    k_wprep_node<<<26 * L, 64, 0, stream>>>(Wup_s, Wup_v, Wout_s, Wout_v,
                                            Wprod_s, Wprod_v, Wsc_s, Wsc_v, Bmats);

    for (int i = 0; i < L; i++) {
        const _Float16* Bl = Bmats + (size_t)i * 26 * 4096;
        k_nodeA<<<NT, 256, 0, stream>>>(s, v, species_s,
                                        Bl, Bl + 4096,
                                        Bl + 6 * 4096, Bl + 16 * 4096,
                                        Wsc_s + (size_t)i * 40960, Wsc_v + (size_t)i * 40960,
                                        (float2*)packh, (float4*)scp, agg0, agg1, N);
        k_msg<<<ET, 256, 0, stream>>>(efT, (const float4*)geo, snd_s, rcv_s,
                                      (const float2*)packh,
                                      B1f + (size_t)i * 2048, B2f + (size_t)i * 4096,
                                      B3f + (size_t)i * 20480, agg0, agg1, E);
        k_nodeB<<<NT, 256, 0, stream>>>(agg0, agg1, species_s, origid,
                                        Bl + 2 * 4096, Bl + 3 * 4096,
                                        Bl + 4 * 4096, Bl + 5 * 4096,
                                        P0 + (size_t)i * 1920, P1 + (size_t)i * 1280,
                                        (const float4*)scp, s, v, out, N, i, L);
    }
}

// Round 10
// 687.764 us; speedup vs baseline: 1.1932x; 1.1932x over previous
//
#include <hip/hip_runtime.h>
#include <hip/hip_bf16.h>
#include <hip/hip_fp16.h>

typedef _Float16 half8 __attribute__((ext_vector_type(8)));
typedef float floatx4 __attribute__((ext_vector_type(4)));

union F2H { float f; _Float16 h[2]; };

__device__ __forceinline__ float siluf(float x) {
    return x / (1.0f + __expf(-x));
}

// ---------------- species per node + histogram (+ deg zero) ----------------
__global__ void k_species(const float* __restrict__ attrs, int* __restrict__ species_o,
                          int* __restrict__ zcount, int* __restrict__ deg, int N) {
    int n = blockIdx.x * 256 + threadIdx.x;
    if (n >= N) return;
    int z = 0;
    #pragma unroll
    for (int k = 1; k < 10; k++) if (attrs[n * 10 + k] > 0.5f) z = k;
    species_o[n] = z;
    deg[n] = 0;
    atomicAdd(&zcount[z], 1);
}

__global__ void k_zscan(const int* __restrict__ zcount, int* __restrict__ zcur) {
    if (threadIdx.x == 0) {
        int run = 0;
        for (int z = 0; z < 10; z++) { zcur[z] = run; run += zcount[z]; }
    }
}

__global__ void k_zperm(const int* __restrict__ species_o, int* __restrict__ zcur,
                        int* __restrict__ perm_n, int* __restrict__ inv_n, int N) {
    int n = blockIdx.x * 256 + threadIdx.x;
    if (n >= N) return;
    int pos = atomicAdd(&zcur[species_o[n]], 1);
    perm_n[pos] = n;
    inv_n[n] = pos;
}

// ---------------- init state in SPECIES-SORTED node order ----------------
__global__ void k_init(const int* __restrict__ perm_n, const int* __restrict__ species_o,
                       const float* __restrict__ Wemb, int* __restrict__ species_s,
                       int* __restrict__ origid, float* __restrict__ s,
                       float* __restrict__ v, int N) {
    int p = blockIdx.x * 4 + (threadIdx.x >> 6);
    if (p >= N) return;
    int lane = threadIdx.x & 63;
    int n = perm_n[p];
    int z = species_o[n];
    if (lane == 0) { species_s[p] = z; origid[p] = n; }
    s[(size_t)p * 64 + lane] = Wemb[z * 64 + lane];
    v[(size_t)p * 192 + lane] = 0.0f;
    v[(size_t)p * 192 + 64 + lane] = 0.0f;
    v[(size_t)p * 192 + 128 + lane] = 0.0f;
}

// ---------------- counting sort of edges by (sorted) receiver ----------------
__global__ void k_hist(const int* __restrict__ ei, const int* __restrict__ inv_n,
                       int* __restrict__ deg, int E) {
    int e = blockIdx.x * 256 + threadIdx.x;
    if (e < E) atomicAdd(&deg[inv_n[ei[E + e]]], 1);
}

__global__ void k_scan(const int* __restrict__ deg, int* __restrict__ rowptr,
                       int* __restrict__ cursor, int N) {
    __shared__ int part[1024];
    int t = threadIdx.x;
    int chunk = (N + 1023) / 1024;
    int lo = t * chunk, hi = min(lo + chunk, N);
    int sum = 0;
    for (int i = lo; i < hi; i++) sum += deg[i];
    part[t] = sum;
    __syncthreads();
    for (int off = 1; off < 1024; off <<= 1) {
        int add = (t >= off) ? part[t - off] : 0;
        __syncthreads();
        part[t] += add;
        __syncthreads();
    }
    int run = (t > 0) ? part[t - 1] : 0;
    for (int i = lo; i < hi; i++) { rowptr[i] = run; cursor[i] = run; run += deg[i]; }
    if (t == 1023) rowptr[N] = part[1023];
}

__global__ void k_eperm(const int* __restrict__ ei, const int* __restrict__ inv_n,
                        int* __restrict__ cursor, int* __restrict__ perm, int E) {
    int e = blockIdx.x * 256 + threadIdx.x;
    if (e < E) {
        int r = inv_n[ei[E + e]];
        int pos = atomicAdd(&cursor[r], 1);
        perm[pos] = e;
    }
}

// ---------------- geometry + radial basis on SORTED edge order ----------------
__global__ void k_geom(const int* __restrict__ ei, const int* __restrict__ perm,
                       const int* __restrict__ inv_n, const float* __restrict__ pos,
                       const float* __restrict__ shifts, float4* __restrict__ geo,
                       _Float16* __restrict__ efT, int* __restrict__ snd_s, int E) {
    int j = blockIdx.x * 64 + threadIdx.x;
    if (j >= E) return;
    int e = perm[j];
    int snd = ei[e], rcv = ei[E + e];
    float dx = pos[rcv * 3 + 0] - pos[snd * 3 + 0] + shifts[e * 3 + 0];
    float dy = pos[rcv * 3 + 1] - pos[snd * 3 + 1] + shifts[e * 3 + 1];
    float dz = pos[rcv * 3 + 2] - pos[snd * 3 + 2] + shifts[e * 3 + 2];
    float r = sqrtf(dx * dx + dy * dy + dz * dz);
    float rin = 1.0f / (r + 1e-9f);
    const float SQ3 = 1.7320508075688772f;
    geo[j] = make_float4(SQ3 * dx * rin, SQ3 * dy * rin, SQ3 * dz * rin, 0.0f);
    snd_s[j] = inv_n[snd];
    float u = r * 0.2f;
    float env = 0.0f;
    if (u < 1.0f) {
        float u2 = u * u;
        float u6 = u2 * u2 * u2;
        env = 1.0f - 28.0f * u6 + 48.0f * u6 * u - 21.0f * u6 * u2;
    }
    const float PIF = 3.14159265358979f;
    float x = PIF * u;
    float sp = __sinf(x), cp = __cosf(x);
    float coef = 0.6324555320336759f * rin * env;
    float sm1 = 0.0f, scur = sp, twoc = 2.0f * cp;
    #pragma unroll
    for (int k = 0; k < 8; k++) {
        efT[k * (size_t)E + j] = (_Float16)(coef * scur);
        float nxt = twoc * scur - sm1;
        sm1 = scur; scur = nxt;
    }
}

// -------- weight prep (edge MLP): RW1/RW2/RW3 -> fp16 B-frag (16x16x32 MFMA) --------
__global__ void k_wprep(const float* __restrict__ RW1, const float* __restrict__ RW2,
                        const float* __restrict__ RW3, _Float16* __restrict__ B1f,
                        _Float16* __restrict__ B2f, _Float16* __restrict__ B3f) {
    int lane = threadIdx.x;
    int t = blockIdx.x;
    int layer = t / 52;
    int tt = t % 52;
    int quad = lane >> 4, colx = lane & 15;
    if (tt < 4) {
        int nt = tt;
        const float* W = RW1 + (size_t)layer * 512;
        _Float16* dst = B1f + (size_t)layer * 2048 + ((size_t)nt * 64 + lane) * 8;
        #pragma unroll
        for (int j = 0; j < 8; j++) {
            int k = quad * 8 + j, n = nt * 16 + colx;
            dst[j] = (k < 8) ? (_Float16)W[k * 64 + n] : (_Float16)0.0f;
        }
    } else if (tt < 12) {
        int u = tt - 4;
        int kt = u >> 2, nt = u & 3;
        const float* W = RW2 + (size_t)layer * 4096;
        _Float16* dst = B2f + (size_t)layer * 4096 + (((size_t)kt * 4 + nt) * 64 + lane) * 8;
        #pragma unroll
        for (int j = 0; j < 8; j++) {
            int k = kt * 32 + quad * 8 + j, n = nt * 16 + colx;
            dst[j] = (_Float16)W[k * 64 + n];
        }
    } else {
        int u = tt - 12;
        int kt = u / 20, nt = u % 20;
        const float* W = RW3 + (size_t)layer * 20480;
        _Float16* dst = B3f + (size_t)layer * 20480 + (((size_t)kt * 20 + nt) * 64 + lane) * 8;
        #pragma unroll
        for (int j = 0; j < 8; j++) {
            int k = kt * 32 + quad * 8 + j, n = nt * 16 + colx;
            dst[j] = (_Float16)W[k * 320 + n];
        }
    }
}

// -------- weight prep (node mats): 64x64 fp32 -> B-frag fp16. 26 mats per layer -----
__global__ void k_wprep_node(const float* __restrict__ Wup_s, const float* __restrict__ Wup_v,
                             const float* __restrict__ Wout_s, const float* __restrict__ Wout_v,
                             const float* __restrict__ Wprod_s, const float* __restrict__ Wprod_v,
                             const float* __restrict__ Wsc_s, const float* __restrict__ Wsc_v,
                             _Float16* __restrict__ Bmats) {
    int mid = blockIdx.x;
    int layer = mid / 26, m = mid % 26;
    const float* src;
    if (m == 0)      src = Wup_s  + (size_t)layer * 4096;
    else if (m == 1) src = Wup_v  + (size_t)layer * 4096;
    else if (m == 2) src = Wout_s + (size_t)layer * 4096;
    else if (m == 3) src = Wout_v + (size_t)layer * 4096;
    else if (m == 4) src = Wprod_s + (size_t)layer * 4096;
    else if (m == 5) src = Wprod_v + (size_t)layer * 4096;
    else if (m < 16) src = Wsc_s + (size_t)layer * 40960 + (size_t)(m - 6) * 4096;
    else             src = Wsc_v + (size_t)layer * 40960 + (size_t)(m - 16) * 4096;
    _Float16* dst = Bmats + (size_t)mid * 4096;
    int lane = threadIdx.x, quad = lane >> 4, colx = lane & 15;
    for (int t = 0; t < 8; t++) {
        int kt = t >> 2, nt = t & 3;
        #pragma unroll
        for (int j = 0; j < 8; j++) {
            int k = kt * 32 + quad * 8 + j, n = nt * 16 + colx;
            dst[(size_t)t * 512 + lane * 8 + j] = (_Float16)src[k * 64 + n];
        }
    }
}

// helper: load A-frag (8 ch of one node) from planar fp32, fp16-convert
__device__ __forceinline__ half8 loadA(const float* __restrict__ base, bool valid) {
    half8 a;
    if (valid) {
        float4 f0 = ((const float4*)base)[0];
        float4 f1 = ((const float4*)base)[1];
        a[0]=(_Float16)f0.x; a[1]=(_Float16)f0.y; a[2]=(_Float16)f0.z; a[3]=(_Float16)f0.w;
        a[4]=(_Float16)f1.x; a[5]=(_Float16)f1.y; a[6]=(_Float16)f1.z; a[7]=(_Float16)f1.w;
    } else {
        #pragma unroll
        for (int j = 0; j < 8; j++) a[j] = (_Float16)0.0f;
    }
    return a;
}

// helper: load 4 A-frags (8 ch, 4 components) from fp16-packed half4 stream
__device__ __forceinline__ void loadAgg4(const float2* __restrict__ base, bool valid,
                                         half8* a0, half8* a1, half8* a2, half8* a3) {
    #pragma unroll
    for (int j = 0; j < 8; j++) {
        _Float16 x0 = (_Float16)0.0f, x1 = x0, x2 = x0, x3 = x0;
        if (valid) {
            float2 p = base[j];
            F2H u1, u2; u1.f = p.x; u2.f = p.y;
            x0 = u1.h[0]; x1 = u1.h[1]; x2 = u2.h[0]; x3 = u2.h[1];
        }
        (*a0)[j] = x0; (*a1)[j] = x1; (*a2)[j] = x2; (*a3)[j] = x3;
    }
}

// ---- node kernel A: up-projection (fp16 pack) + species skip (fp16 scph) ----
__global__ __launch_bounds__(256, 4)
void k_nodeA(const float* __restrict__ s, const float* __restrict__ v,
             const int* __restrict__ species,
             const _Float16* __restrict__ Bup_s, const _Float16* __restrict__ Bup_v,
             const _Float16* __restrict__ Bsc_s, const _Float16* __restrict__ Bsc_v,
             const float* __restrict__ Wsc_s32, const float* __restrict__ Wsc_v32,
             float2* __restrict__ packh, float2* __restrict__ scph, int N) {
    const int tid = threadIdx.x;
    const int lane = tid & 63, wave = tid >> 6;
    const int quad = lane >> 4, col = lane & 15;
    const int n0 = blockIdx.x * 64 + wave * 16;
    if (n0 >= N) return;   // no barriers in this kernel

    half8 as[2], av0[2], av1[2], av2[2];
    int node = n0 + col;
    bool vn = node < N;
    const float* sp = s + (size_t)(vn ? node : 0) * 64;
    const float* vp = v + (size_t)(vn ? node : 0) * 192;
    #pragma unroll
    for (int kt = 0; kt < 2; kt++) {
        int kb = kt * 32 + quad * 8;
        as[kt]  = loadA(sp + kb, vn);
        av0[kt] = loadA(vp + kb, vn);
        av1[kt] = loadA(vp + 64 + kb, vn);
        av2[kt] = loadA(vp + 128 + kb, vn);
    }

    // up-projection -> fp16 pack
    #pragma unroll
    for (int nt = 0; nt < 4; nt++) {
        floatx4 cs = {0,0,0,0}, c0 = {0,0,0,0}, c1 = {0,0,0,0}, c2 = {0,0,0,0};
        #pragma unroll
        for (int kt = 0; kt < 2; kt++) {
            half8 bs = *(const half8*)(Bup_s + (((size_t)kt * 4 + nt) * 64 + lane) * 8);
            half8 bv = *(const half8*)(Bup_v + (((size_t)kt * 4 + nt) * 64 + lane) * 8);
            cs = __builtin_amdgcn_mfma_f32_16x16x32_f16(as[kt],  bs, cs, 0, 0, 0);
            c0 = __builtin_amdgcn_mfma_f32_16x16x32_f16(av0[kt], bv, c0, 0, 0, 0);
            c1 = __builtin_amdgcn_mfma_f32_16x16x32_f16(av1[kt], bv, c1, 0, 0, 0);
            c2 = __builtin_amdgcn_mfma_f32_16x16x32_f16(av2[kt], bv, c2, 0, 0, 0);
        }
        int ch = nt * 16 + col;
        #pragma unroll
        for (int r = 0; r < 4; r++) {
            int n = n0 + quad * 4 + r;
            if (n < N) {
                F2H u1, u2;
                u1.h[0] = (_Float16)cs[r]; u1.h[1] = (_Float16)c0[r];
                u2.h[0] = (_Float16)c1[r]; u2.h[1] = (_Float16)c2[r];
                packh[(size_t)n * 64 + ch] = make_float2(u1.f, u2.f);
            }
        }
    }

    // species skip connection -> scph (fp16)
    int zlo = species[n0];
    int zhi = species[min(n0 + 15, N - 1)];
    if (zlo == zhi) {
        const _Float16* Bs = Bsc_s + (size_t)zlo * 4096;
        const _Float16* Bv = Bsc_v + (size_t)zlo * 4096;
        #pragma unroll
        for (int nt = 0; nt < 4; nt++) {
            floatx4 cs = {0,0,0,0}, c0 = {0,0,0,0}, c1 = {0,0,0,0}, c2 = {0,0,0,0};
            #pragma unroll
            for (int kt = 0; kt < 2; kt++) {
                half8 bs = *(const half8*)(Bs + (((size_t)kt * 4 + nt) * 64 + lane) * 8);
                half8 bv = *(const half8*)(Bv + (((size_t)kt * 4 + nt) * 64 + lane) * 8);
                cs = __builtin_amdgcn_mfma_f32_16x16x32_f16(as[kt],  bs, cs, 0, 0, 0);
                c0 = __builtin_amdgcn_mfma_f32_16x16x32_f16(av0[kt], bv, c0, 0, 0, 0);
                c1 = __builtin_amdgcn_mfma_f32_16x16x32_f16(av1[kt], bv, c1, 0, 0, 0);
                c2 = __builtin_amdgcn_mfma_f32_16x16x32_f16(av2[kt], bv, c2, 0, 0, 0);
            }
            int ch = nt * 16 + col;
            #pragma unroll
            for (int r = 0; r < 4; r++) {
                int n = n0 + quad * 4 + r;
                if (n < N) {
                    F2H u1, u2;
                    u1.h[0] = (_Float16)cs[r]; u1.h[1] = (_Float16)c0[r];
                    u2.h[0] = (_Float16)c1[r]; u2.h[1] = (_Float16)c2[r];
                    scph[(size_t)n * 64 + ch] = make_float2(u1.f, u2.f);
                }
            }
        }
    } else {
        for (int m = 0; m < 16; m++) {
            int n = n0 + m;
            if (n >= N) break;
            int z = species[n];
            const float* Ws = Wsc_s32 + (size_t)z * 4096;
            const float* Wv = Wsc_v32 + (size_t)z * 4096;
            float sv = s[(size_t)n * 64 + lane];
            float w0 = v[(size_t)n * 192 + lane];
            float w1 = v[(size_t)n * 192 + 64 + lane];
            float w2 = v[(size_t)n * 192 + 128 + lane];
            float a = 0, b0 = 0, b1 = 0, b2 = 0;
            for (int c = 0; c < 64; c++) {
                float ws = Ws[c * 64 + lane], wv = Wv[c * 64 + lane];
                a  = fmaf(__shfl(sv, c), ws, a);
                b0 = fmaf(__shfl(w0, c), wv, b0);
                b1 = fmaf(__shfl(w1, c), wv, b1);
                b2 = fmaf(__shfl(w2, c), wv, b2);
            }
            F2H u1, u2;
            u1.h[0] = (_Float16)a;  u1.h[1] = (_Float16)b0;
            u2.h[0] = (_Float16)b1; u2.h[1] = (_Float16)b2;
            scph[(size_t)n * 64 + lane] = make_float2(u1.f, u2.f);
        }
    }
}

// ---- message kernel: MFMA edge-MLP (round-8 structure), fp16 inputs, msg buffer ----
#define ROWP 72
__global__ __launch_bounds__(256, 4)
void k_msg(const int* __restrict__ rowptr, int na, int nb,
           const _Float16* __restrict__ efT, const float4* __restrict__ geo,
           const int* __restrict__ snd_s, const float2* __restrict__ packh,
           const _Float16* __restrict__ B1f, const _Float16* __restrict__ B2f,
           const _Float16* __restrict__ B3f, float2* __restrict__ msg,
           int cap, int E) {
    __shared__ _Float16 a2[4 * 16 * ROWP];
    __shared__ _Float16 a3[4 * 16 * ROWP];
    const int tid = threadIdx.x;
    const int lane = tid & 63;
    const int wave = tid >> 6;
    const int quad = lane >> 4;
    const int col = lane & 15;
    const int Jlo = rowptr[na], Jhi = rowptr[nb];
    const int j0 = Jlo + blockIdx.x * 64 + wave * 16;

    _Float16* a2w = a2 + wave * 16 * ROWP;
    _Float16* a3w = a3 + wave * 16 * ROWP;

    // ---- stage 1: h1 = silu(ef @ RW1) (K padded 8->32) ----
    half8 aef;
    #pragma unroll
    for (int k = 0; k < 8; k++) aef[k] = (_Float16)0.0f;
    if (quad == 0) {
        int je = j0 + col;
        if (je < Jhi) {
            #pragma unroll
            for (int k = 0; k < 8; k++) aef[k] = efT[(size_t)k * E + je];
        }
    }
    {
        floatx4 c1[4];
        #pragma unroll
        for (int nt = 0; nt < 4; nt++) {
            c1[nt] = (floatx4){0.0f, 0.0f, 0.0f, 0.0f};
            half8 b = *(const half8*)(B1f + ((size_t)nt * 64 + lane) * 8);
            c1[nt] = __builtin_amdgcn_mfma_f32_16x16x32_f16(aef, b, c1[nt], 0, 0, 0);
        }
        #pragma unroll
        for (int nt = 0; nt < 4; nt++)
            #pragma unroll
            for (int r = 0; r < 4; r++)
                a2w[(quad * 4 + r) * ROWP + nt * 16 + col] = (_Float16)siluf(c1[nt][r]);
    }
    __syncthreads();

    // ---- stage 2: h2 = silu(h1 @ RW2) ----
    {
        half8 af0 = *(const half8*)&a2w[col * ROWP + quad * 8];
        half8 af1 = *(const half8*)&a2w[col * ROWP + 32 + quad * 8];
        floatx4 c2[4];
        #pragma unroll
        for (int nt = 0; nt < 4; nt++) {
            c2[nt] = (floatx4){0.0f, 0.0f, 0.0f, 0.0f};
            half8 b0 = *(const half8*)(B2f + (((size_t)0 * 4 + nt) * 64 + lane) * 8);
            half8 b1 = *(const half8*)(B2f + (((size_t)1 * 4 + nt) * 64 + lane) * 8);
            c2[nt] = __builtin_amdgcn_mfma_f32_16x16x32_f16(af0, b0, c2[nt], 0, 0, 0);
            c2[nt] = __builtin_amdgcn_mfma_f32_16x16x32_f16(af1, b1, c2[nt], 0, 0, 0);
        }
        #pragma unroll
        for (int nt = 0; nt < 4; nt++)
            #pragma unroll
            for (int r = 0; r < 4; r++)
                a3w[(quad * 4 + r) * ROWP + nt * 16 + col] = (_Float16)siluf(c2[nt][r]);
    }
    __syncthreads();

    // ---- stage 3: w = h2 @ RW3 per 16-channel block + fused message epilogue ----
    const float inv32 = 1.0f / 32.0f;
    const float is3 = 0.5773502691896258f;
    const float is2 = 0.7071067811865476f;
    half8 a3f0 = *(const half8*)&a3w[col * ROWP + quad * 8];
    half8 a3f1 = *(const half8*)&a3w[col * ROWP + 32 + quad * 8];

    for (int cb = 0; cb < 4; cb++) {
        floatx4 acc[5];
        #pragma unroll
        for (int q = 0; q < 5; q++) {
            acc[q] = (floatx4){0.0f, 0.0f, 0.0f, 0.0f};
            int nt = q * 4 + cb;
            half8 b0 = *(const half8*)(B3f + (((size_t)0 * 20 + nt) * 64 + lane) * 8);
            half8 b1 = *(const half8*)(B3f + (((size_t)1 * 20 + nt) * 64 + lane) * 8);
            acc[q] = __builtin_amdgcn_mfma_f32_16x16x32_f16(a3f0, b0, acc[q], 0, 0, 0);
            acc[q] = __builtin_amdgcn_mfma_f32_16x16x32_f16(a3f1, b1, acc[q], 0, 0, 0);
        }
        const int c = cb * 16 + col;
        #pragma unroll
        for (int r = 0; r < 4; r++) {
            int m = quad * 4 + r;
            int jj = j0 + m;
            if (jj < Jhi) {
                int idx = jj - Jlo;
                if (idx < cap) {
                    int snd = snd_s[jj];
                    float4 g = geo[jj];
                    float2 pp = packh[(size_t)snd * 64 + c];
                    F2H u1, u2; u1.f = pp.x; u2.f = pp.y;
                    float pvx = (float)u1.h[0], pvy = (float)u1.h[1];
                    float pvz = (float)u2.h[0], pvw = (float)u2.h[1];
                    float w00 = acc[0][r], w110 = acc[1][r], w011 = acc[2][r];
                    float w101 = acc[3][r], w111 = acc[4][r];
                    float dvy = pvy * g.x + pvz * g.y + pvw * g.z;
                    float m0 = (w00 * pvx + w110 * dvy * is3) * inv32;
                    float cxv = pvz * g.z - pvw * g.y;
                    float cyv = pvw * g.x - pvy * g.z;
                    float czv = pvy * g.y - pvz * g.x;
                    float m1x = (w011 * pvx * g.x + w101 * pvy + w111 * cxv * is2) * inv32;
                    float m1y = (w011 * pvx * g.y + w101 * pvz + w111 * cyv * is2) * inv32;
                    float m1z = (w011 * pvx * g.z + w101 * pvw + w111 * czv * is2) * inv32;
                    F2H o1, o2;
                    o1.h[0] = (_Float16)m0;  o1.h[1] = (_Float16)m1x;
                    o2.h[0] = (_Float16)m1y; o2.h[1] = (_Float16)m1z;
                    msg[(size_t)idx * 64 + c] = make_float2(o1.f, o2.f);
                }
            }
        }
    }
}

// ---------------- CSR aggregation: wave per node, lane = channel; fp16 out ----------
__global__ void k_agg(const float2* __restrict__ msg, const int* __restrict__ rowptr,
                      float2* __restrict__ aggh, int na, int nb, int cap) {
    int n = na + blockIdx.x * 4 + (threadIdx.x >> 6);
    int lane = threadIdx.x & 63;
    if (n >= nb) return;
    int Jlo = rowptr[na];
    int j0 = rowptr[n], j1 = rowptr[n + 1];
    float a0 = 0.0f, a1 = 0.0f, a2 = 0.0f, a3 = 0.0f;
    for (int j = j0; j < j1; j++) {
        int idx = j - Jlo;
        if (idx >= cap) break;
        float2 m = msg[(size_t)idx * 64 + lane];
        F2H u1, u2; u1.f = m.x; u2.f = m.y;
        a0 += (float)u1.h[0]; a1 += (float)u1.h[1];
        a2 += (float)u2.h[0]; a3 += (float)u2.h[1];
    }
    F2H o1, o2;
    o1.h[0] = (_Float16)a0; o1.h[1] = (_Float16)a1;
    o2.h[0] = (_Float16)a2; o2.h[1] = (_Float16)a3;
    aggh[(size_t)n * 64 + lane] = make_float2(o1.f, o2.f);
}

// ---- node kernel B: Wout MFMA -> P0/P1 epilogue -> LDS transpose -> Wprod MFMA -----
#define ROWPB 72
__global__ __launch_bounds__(256, 4)
void k_nodeB(const float2* __restrict__ aggh,
             const int* __restrict__ species, const int* __restrict__ origid,
             const _Float16* __restrict__ Bout_s, const _Float16* __restrict__ Bout_v,
             const _Float16* __restrict__ Bprod_s, const _Float16* __restrict__ Bprod_v,
             const float* __restrict__ P0l, const float* __restrict__ P1l,
             const float2* __restrict__ scph, float* __restrict__ s,
             float* __restrict__ v, float* __restrict__ out,
             int N, int layer, int Ltot) {
    __shared__ _Float16 lds[4 * 4 * 16 * ROWPB];
    const int tid = threadIdx.x;
    const int lane = tid & 63, wave = tid >> 6;
    const int quad = lane >> 4, col = lane & 15;
    const int n0 = blockIdx.x * 64 + wave * 16;
    const bool act = n0 < N;
    _Float16* lw = lds + wave * 4 * 16 * ROWPB;

    if (act) {
        half8 as[2], av0[2], av1[2], av2[2];
        int node = n0 + col;
        bool vn = node < N;
        const float2* ab = aggh + (size_t)(vn ? node : 0) * 64;
        #pragma unroll
        for (int kt = 0; kt < 2; kt++) {
            int kb = kt * 32 + quad * 8;
            loadAgg4(ab + kb, vn, &as[kt], &av0[kt], &av1[kt], &av2[kt]);
        }
        #pragma unroll
        for (int nt = 0; nt < 4; nt++) {
            floatx4 cs = {0,0,0,0}, c0 = {0,0,0,0}, c1 = {0,0,0,0}, c2 = {0,0,0,0};
            #pragma unroll
            for (int kt = 0; kt < 2; kt++) {
                half8 bs = *(const half8*)(Bout_s + (((size_t)kt * 4 + nt) * 64 + lane) * 8);
                half8 bv = *(const half8*)(Bout_v + (((size_t)kt * 4 + nt) * 64 + lane) * 8);
                cs = __builtin_amdgcn_mfma_f32_16x16x32_f16(as[kt],  bs, cs, 0, 0, 0);
                c0 = __builtin_amdgcn_mfma_f32_16x16x32_f16(av0[kt], bv, c0, 0, 0, 0);
                c1 = __builtin_amdgcn_mfma_f32_16x16x32_f16(av1[kt], bv, c1, 0, 0, 0);
                c2 = __builtin_amdgcn_mfma_f32_16x16x32_f16(av2[kt], bv, c2, 0, 0, 0);
            }
            int ch = nt * 16 + col;
            #pragma unroll
            for (int r = 0; r < 4; r++) {
                int nl = quad * 4 + r;
                int n = n0 + nl;
                float ps = 0.0f, p0v = 0.0f, p1v = 0.0f, p2v = 0.0f;
                if (n < N) {
                    int z = species[n];
                    const float* p = P0l + ((size_t)z * 64 + ch) * 3;
                    const float* q = P1l + ((size_t)z * 64 + ch) * 2;
                    float msv = cs[r];
                    float m0 = c0[r], m1 = c1[r], m2 = c2[r];
                    ps = p[0] * msv + p[1] * msv * msv + p[2] * (m0 * m0 + m1 * m1 + m2 * m2);
                    float qq = q[0] + q[1] * msv;
                    p0v = qq * m0; p1v = qq * m1; p2v = qq * m2;
                }
                lw[0 * 16 * ROWPB + nl * ROWPB + ch] = (_Float16)ps;
                lw[1 * 16 * ROWPB + nl * ROWPB + ch] = (_Float16)p0v;
                lw[2 * 16 * ROWPB + nl * ROWPB + ch] = (_Float16)p1v;
                lw[3 * 16 * ROWPB + nl * ROWPB + ch] = (_Float16)p2v;
            }
        }
    }
    __syncthreads();
    if (act) {
        half8 as[2], av0[2], av1[2], av2[2];
        #pragma unroll
        for (int kt = 0; kt < 2; kt++) {
            int kb = kt * 32 + quad * 8;
            as[kt]  = *(const half8*)&lw[0 * 16 * ROWPB + col * ROWPB + kb];
            av0[kt] = *(const half8*)&lw[1 * 16 * ROWPB + col * ROWPB + kb];
            av1[kt] = *(const half8*)&lw[2 * 16 * ROWPB + col * ROWPB + kb];
            av2[kt] = *(const half8*)&lw[3 * 16 * ROWPB + col * ROWPB + kb];
        }
        #pragma unroll
        for (int nt = 0; nt < 4; nt++) {
            floatx4 cs = {0,0,0,0}, c0 = {0,0,0,0}, c1 = {0,0,0,0}, c2 = {0,0,0,0};
            #pragma unroll
            for (int kt = 0; kt < 2; kt++) {
                half8 bs = *(const half8*)(Bprod_s + (((size_t)kt * 4 + nt) * 64 + lane) * 8);
                half8 bv = *(const half8*)(Bprod_v + (((size_t)kt * 4 + nt) * 64 + lane) * 8);
                cs = __builtin_amdgcn_mfma_f32_16x16x32_f16(as[kt],  bs, cs, 0, 0, 0);
                c0 = __builtin_amdgcn_mfma_f32_16x16x32_f16(av0[kt], bv, c0, 0, 0, 0);
                c1 = __builtin_amdgcn_mfma_f32_16x16x32_f16(av1[kt], bv, c1, 0, 0, 0);
                c2 = __builtin_amdgcn_mfma_f32_16x16x32_f16(av2[kt], bv, c2, 0, 0, 0);
            }
            int ch = nt * 16 + col;
            #pragma unroll
            for (int r = 0; r < 4; r++) {
                int n = n0 + quad * 4 + r;
                if (n < N) {
                    float2 scv = scph[(size_t)n * 64 + ch];
                    F2H u1, u2; u1.f = scv.x; u2.f = scv.y;
                    float sval = cs[r] + (float)u1.h[0];
                    s[(size_t)n * 64 + ch] = sval;
                    v[(size_t)n * 192 + ch] = c0[r] + (float)u1.h[1];
                    v[(size_t)n * 192 + 64 + ch] = c1[r] + (float)u2.h[0];
                    v[(size_t)n * 192 + 128 + ch] = c2[r] + (float)u2.h[1];
                    out[(size_t)origid[n] * (Ltot * 64) + layer * 64 + ch] = sval;
                }
            }
        }
    }
}

extern "C" void kernel_launch(void* const* d_in, const int* in_sizes, int n_in,
                              void* d_out, int out_size, void* d_ws, size_t ws_size,
                              hipStream_t stream) {
    const float* node_attrs = (const float*)d_in[0];
    const float* atom_pos   = (const float*)d_in[1];
    const float* shifts     = (const float*)d_in[2];
    const float* W_embed    = (const float*)d_in[3];
    const float* Wup_s      = (const float*)d_in[4];
    const float* Wup_v      = (const float*)d_in[5];
    const float* RW1        = (const float*)d_in[6];
    const float* RW2        = (const float*)d_in[7];
    const float* RW3        = (const float*)d_in[8];
    const float* Wout_s     = (const float*)d_in[9];
    const float* Wout_v     = (const float*)d_in[10];
    const float* Wsc_s      = (const float*)d_in[11];
    const float* Wsc_v      = (const float*)d_in[12];
    const float* P0         = (const float*)d_in[13];
    const float* P1         = (const float*)d_in[14];
    const float* Wprod_s    = (const float*)d_in[15];
    const float* Wprod_v    = (const float*)d_in[16];
    const int*   ei         = (const int*)d_in[17];

    const int N = in_sizes[0] / 10;
    const int E = in_sizes[17] / 2;
    const int L = in_sizes[4] / 4096;
    float* out = (float*)d_out;

    char* wsb = (char*)d_ws;
    size_t off = 0;
    auto alloci = [&](size_t n) {
        int* p = (int*)(wsb + off);
        off = (off + n * 4 + 255) / 256 * 256;
        return p;
    };
    auto allocf = [&](size_t n) {
        float* p = (float*)(wsb + off);
        off = (off + n * 4 + 255) / 256 * 256;
        return p;
    };
    auto alloch = [&](size_t n) {
        _Float16* p = (_Float16*)(wsb + off);
        off = (off + n * 2 + 255) / 256 * 256;
        return p;
    };
    int* species_o = alloci(N);
    int* species_s = alloci(N);
    int* zcount    = alloci(16);
    int* zcur      = alloci(16);
    int* perm_n    = alloci(N);
    int* inv_n     = alloci(N);
    int* origid    = alloci(N);
    int* deg       = alloci(N);
    int* rowptr    = alloci(N + 1);
    int* cursor    = alloci(N);
    int* perm      = alloci(E);
    int* snd_s     = alloci(E);
    float* s     = allocf((size_t)N * 64);
    float* v     = allocf((size_t)N * 192);
    float* geo   = allocf((size_t)E * 4);
    _Float16* efT = alloch((size_t)E * 8);
    float* packh = allocf((size_t)N * 128);   // fp16 half4 per (node, ch)
    float* scph  = allocf((size_t)N * 128);   // fp16 half4 per (node, ch)
    float* agghf = allocf((size_t)N * 128);   // fp16 half4 per (node, ch)
    _Float16* B1f   = alloch((size_t)L * 2048);
    _Float16* B2f   = alloch((size_t)L * 4096);
    _Float16* B3f   = alloch((size_t)L * 20480);
    _Float16* Bmats = alloch((size_t)L * 26 * 4096);

    // pick NCHUNK at runtime from ws_size (constant per session -> graph-safe)
    int NCHUNK = 16;
    int cap = 0;
    {
        const int cands[8] = {1, 2, 3, 4, 6, 8, 12, 16};
        for (int ci = 0; ci < 8; ci++) {
            int c = cands[ci];
            int thiscap = (c == 1) ? E : (E / c) * 5 / 4 + 256;
            size_t need = off + (size_t)thiscap * 512;
            if (need <= ws_size) { NCHUNK = c; cap = thiscap; break; }
        }
        if (cap == 0) { NCHUNK = 16; cap = (E / 16) * 5 / 4 + 256; }
    }
    float* msg = allocf((size_t)cap * 128);   // fp16 half4 per (edge, ch)
    (void)n_in; (void)out_size;

    const int NT = (N + 63) / 64;
    const int NB = (N + 255) / 256;
    const int ET = (E + 63) / 64;
    const int EB = (E + 255) / 256;
    const int MT = (cap + 63) / 64;

    hipMemsetAsync(zcount, 0, 16 * sizeof(int), stream);
    k_species<<<NB, 256, 0, stream>>>(node_attrs, species_o, zcount, deg, N);
    k_zscan<<<1, 64, 0, stream>>>(zcount, zcur);
    k_zperm<<<NB, 256, 0, stream>>>(species_o, zcur, perm_n, inv_n, N);
    k_init<<<(N + 3) / 4, 256, 0, stream>>>(perm_n, species_o, W_embed, species_s,
                                            origid, s, v, N);
    k_hist<<<EB, 256, 0, stream>>>(ei, inv_n, deg, E);
    k_scan<<<1, 1024, 0, stream>>>(deg, rowptr, cursor, N);
    k_eperm<<<EB, 256, 0, stream>>>(ei, inv_n, cursor, perm, E);
    k_geom<<<ET, 64, 0, stream>>>(ei, perm, inv_n, atom_pos, shifts,
                                  (float4*)geo, efT, snd_s, E);
    k_wprep<<<52 * L, 64, 0, stream>>>(RW1, RW2, RW3, B1f, B2f, B3f);
    k_wprep_node<<<26 * L, 64, 0, stream>>>(Wup_s, Wup_v, Wout_s, Wout_v,
                                            Wprod_s, Wprod_v, Wsc_s, Wsc_v, Bmats);

    int nbound[17];
    for (int k = 0; k <= NCHUNK; k++) nbound[k] = (int)((long long)N * k / NCHUNK);

    for (int i = 0; i < L; i++) {
        const _Float16* Bl = Bmats + (size_t)i * 26 * 4096;
        k_nodeA<<<NT, 256, 0, stream>>>(s, v, species_s,
                                        Bl, Bl + 4096,
                                        Bl + 6 * 4096, Bl + 16 * 4096,
                                        Wsc_s + (size_t)i * 40960, Wsc_v + (size_t)i * 40960,
                                        (float2*)packh, (float2*)scph, N);
        for (int k = 0; k < NCHUNK; k++) {
            int na = nbound[k], nb = nbound[k + 1];
            k_msg<<<MT, 256, 0, stream>>>(rowptr, na, nb, efT, (const float4*)geo, snd_s,
                                          (const float2*)packh,
                                          B1f + (size_t)i * 2048, B2f + (size_t)i * 4096,
                                          B3f + (size_t)i * 20480, (float2*)msg, cap, E);
            int cnt = nb - na;
            k_agg<<<(cnt + 3) / 4, 256, 0, stream>>>((const float2*)msg, rowptr,
                                                     (float2*)agghf, na, nb, cap);
        }
        k_nodeB<<<NT, 256, 0, stream>>>((const float2*)agghf, species_s, origid,
                                        Bl + 2 * 4096, Bl + 3 * 4096,
                                        Bl + 4 * 4096, Bl + 5 * 4096,
                                        P0 + (size_t)i * 1920, P1 + (size_t)i * 1280,
                                        (const float2*)scph, s, v, out, N, i, L);
    }
}

// Round 11
// 644.281 us; speedup vs baseline: 1.2737x; 1.0675x over previous
//
#include <hip/hip_runtime.h>
#include <hip/hip_bf16.h>
#include <hip/hip_fp16.h>

typedef _Float16 half8 __attribute__((ext_vector_type(8)));
typedef float floatx4 __attribute__((ext_vector_type(4)));

union F2H { float f; _Float16 h[2]; };
union D2F2 { double d; float2 v; };

__device__ __forceinline__ float siluf(float x) {
    return x / (1.0f + __expf(-x));
}

// ---------------- species per node + histogram ----------------
__global__ void k_species(const float* __restrict__ attrs, int* __restrict__ species_o,
                          int* __restrict__ zcount, int N) {
    int n = blockIdx.x * 256 + threadIdx.x;
    if (n >= N) return;
    int z = 0;
    #pragma unroll
    for (int k = 1; k < 10; k++) if (attrs[n * 10 + k] > 0.5f) z = k;
    species_o[n] = z;
    atomicAdd(&zcount[z], 1);
}

// bucket starts rounded up to 16-node tiles
__global__ void k_zscan(const int* __restrict__ zcount, int* __restrict__ zcur,
                        int* __restrict__ zstart) {
    if (threadIdx.x == 0) {
        int run = 0;
        for (int z = 0; z < 10; z++) {
            zstart[z] = run;
            zcur[z] = run;
            run += (zcount[z] + 15) & ~15;
        }
        zstart[10] = run;
    }
}

__global__ void k_zperm(const int* __restrict__ species_o, int* __restrict__ zcur,
                        int* __restrict__ perm_n, int* __restrict__ inv_n, int N) {
    int n = blockIdx.x * 256 + threadIdx.x;
    if (n >= N) return;
    int pos = atomicAdd(&zcur[species_o[n]], 1);
    perm_n[pos] = n;
    inv_n[n] = pos;
}

// mark pad slots (perm_n=-1, species filled for tile uniformity), zero deg everywhere
__global__ void k_padmark(const int* __restrict__ zstart, const int* __restrict__ zcur,
                          int* __restrict__ perm_n, int* __restrict__ deg,
                          int* __restrict__ species_s, int Npad) {
    int p = blockIdx.x * 256 + threadIdx.x;
    if (p >= Npad) return;
    deg[p] = 0;
    if (p >= zstart[10]) {             // tail beyond all buckets
        perm_n[p] = -1;
        species_s[p] = 9;
        return;
    }
    int z = 9;
    #pragma unroll
    for (int q = 0; q < 10; q++) {
        if (p < zstart[q + 1]) { z = q; break; }
    }
    if (p >= zcur[z]) {                // pad inside bucket z
        perm_n[p] = -1;
        species_s[p] = z;
    }
}

// ---------------- init state in SPECIES-SORTED (padded) node order ----------------
__global__ void k_init(const int* __restrict__ perm_n, const int* __restrict__ species_o,
                       const float* __restrict__ Wemb, int* __restrict__ species_s,
                       int* __restrict__ origid, float* __restrict__ s,
                       float* __restrict__ v, int Npad) {
    int p = blockIdx.x * 4 + (threadIdx.x >> 6);
    if (p >= Npad) return;
    int lane = threadIdx.x & 63;
    int n = perm_n[p];
    if (n < 0) {
        if (lane == 0) origid[p] = -1;
        s[(size_t)p * 64 + lane] = 0.0f;
        v[(size_t)p * 192 + lane] = 0.0f;
        v[(size_t)p * 192 + 64 + lane] = 0.0f;
        v[(size_t)p * 192 + 128 + lane] = 0.0f;
        return;
    }
    int z = species_o[n];
    if (lane == 0) { species_s[p] = z; origid[p] = n; }
    s[(size_t)p * 64 + lane] = Wemb[z * 64 + lane];
    v[(size_t)p * 192 + lane] = 0.0f;
    v[(size_t)p * 192 + 64 + lane] = 0.0f;
    v[(size_t)p * 192 + 128 + lane] = 0.0f;
}

// ---------------- counting sort of edges by (sorted) receiver ----------------
__global__ void k_hist(const int* __restrict__ ei, const int* __restrict__ inv_n,
                       int* __restrict__ deg, int E) {
    int e = blockIdx.x * 256 + threadIdx.x;
    if (e < E) atomicAdd(&deg[inv_n[ei[E + e]]], 1);
}

__global__ void k_scan(const int* __restrict__ deg, int* __restrict__ rowptr,
                       int* __restrict__ cursor, int N) {
    __shared__ int part[1024];
    int t = threadIdx.x;
    int chunk = (N + 1023) / 1024;
    int lo = t * chunk, hi = min(lo + chunk, N);
    int sum = 0;
    for (int i = lo; i < hi; i++) sum += deg[i];
    part[t] = sum;
    __syncthreads();
    for (int off = 1; off < 1024; off <<= 1) {
        int add = (t >= off) ? part[t - off] : 0;
        __syncthreads();
        part[t] += add;
        __syncthreads();
    }
    int run = (t > 0) ? part[t - 1] : 0;
    for (int i = lo; i < hi; i++) { rowptr[i] = run; cursor[i] = run; run += deg[i]; }
    if (t == 1023) rowptr[N] = part[1023];
}

__global__ void k_eperm(const int* __restrict__ ei, const int* __restrict__ inv_n,
                        int* __restrict__ cursor, int* __restrict__ perm, int E) {
    int e = blockIdx.x * 256 + threadIdx.x;
    if (e < E) {
        int r = inv_n[ei[E + e]];
        int pos = atomicAdd(&cursor[r], 1);
        perm[pos] = e;
    }
}

// ---------------- geometry + radial basis; ef in EDGE-MAJOR fp16 ----------------
__global__ void k_geom(const int* __restrict__ ei, const int* __restrict__ perm,
                       const int* __restrict__ inv_n, const float* __restrict__ pos,
                       const float* __restrict__ shifts, float4* __restrict__ geo,
                       _Float16* __restrict__ efh, int* __restrict__ snd_s, int E) {
    int j = blockIdx.x * 256 + threadIdx.x;
    if (j >= E) return;
    int e = perm[j];
    int snd = ei[e], rcv = ei[E + e];
    float dx = pos[rcv * 3 + 0] - pos[snd * 3 + 0] + shifts[e * 3 + 0];
    float dy = pos[rcv * 3 + 1] - pos[snd * 3 + 1] + shifts[e * 3 + 1];
    float dz = pos[rcv * 3 + 2] - pos[snd * 3 + 2] + shifts[e * 3 + 2];
    float r = sqrtf(dx * dx + dy * dy + dz * dz);
    float rin = 1.0f / (r + 1e-9f);
    const float SQ3 = 1.7320508075688772f;
    geo[j] = make_float4(SQ3 * dx * rin, SQ3 * dy * rin, SQ3 * dz * rin, 0.0f);
    snd_s[j] = inv_n[snd];
    float u = r * 0.2f;
    float env = 0.0f;
    if (u < 1.0f) {
        float u2 = u * u;
        float u6 = u2 * u2 * u2;
        env = 1.0f - 28.0f * u6 + 48.0f * u6 * u - 21.0f * u6 * u2;
    }
    const float PIF = 3.14159265358979f;
    float x = PIF * u;
    float sp = __sinf(x), cp = __cosf(x);
    float coef = 0.6324555320336759f * rin * env;
    float sm1 = 0.0f, scur = sp, twoc = 2.0f * cp;
    half8 e8;
    #pragma unroll
    for (int k = 0; k < 8; k++) {
        e8[k] = (_Float16)(coef * scur);
        float nxt = twoc * scur - sm1;
        sm1 = scur; scur = nxt;
    }
    *(half8*)(efh + (size_t)j * 8) = e8;
}

// -------- weight prep (edge MLP): RW1/RW2/RW3 -> fp16 B-frag (16x16x32 MFMA) --------
__global__ void k_wprep(const float* __restrict__ RW1, const float* __restrict__ RW2,
                        const float* __restrict__ RW3, _Float16* __restrict__ B1f,
                        _Float16* __restrict__ B2f, _Float16* __restrict__ B3f) {
    int lane = threadIdx.x;
    int t = blockIdx.x;
    int layer = t / 52;
    int tt = t % 52;
    int quad = lane >> 4, colx = lane & 15;
    if (tt < 4) {
        int nt = tt;
        const float* W = RW1 + (size_t)layer * 512;
        _Float16* dst = B1f + (size_t)layer * 2048 + ((size_t)nt * 64 + lane) * 8;
        #pragma unroll
        for (int j = 0; j < 8; j++) {
            int k = quad * 8 + j, n = nt * 16 + colx;
            dst[j] = (k < 8) ? (_Float16)W[k * 64 + n] : (_Float16)0.0f;
        }
    } else if (tt < 12) {
        int u = tt - 4;
        int kt = u >> 2, nt = u & 3;
        const float* W = RW2 + (size_t)layer * 4096;
        _Float16* dst = B2f + (size_t)layer * 4096 + (((size_t)kt * 4 + nt) * 64 + lane) * 8;
        #pragma unroll
        for (int j = 0; j < 8; j++) {
            int k = kt * 32 + quad * 8 + j, n = nt * 16 + colx;
            dst[j] = (_Float16)W[k * 64 + n];
        }
    } else {
        int u = tt - 12;
        int kt = u / 20, nt = u % 20;
        const float* W = RW3 + (size_t)layer * 20480;
        _Float16* dst = B3f + (size_t)layer * 20480 + (((size_t)kt * 20 + nt) * 64 + lane) * 8;
        #pragma unroll
        for (int j = 0; j < 8; j++) {
            int k = kt * 32 + quad * 8 + j, n = nt * 16 + colx;
            dst[j] = (_Float16)W[k * 320 + n];
        }
    }
}

// -------- weight prep (node mats): 64x64 fp32 -> B-frag fp16. 26 mats per layer -----
__global__ void k_wprep_node(const float* __restrict__ Wup_s, const float* __restrict__ Wup_v,
                             const float* __restrict__ Wout_s, const float* __restrict__ Wout_v,
                             const float* __restrict__ Wprod_s, const float* __restrict__ Wprod_v,
                             const float* __restrict__ Wsc_s, const float* __restrict__ Wsc_v,
                             _Float16* __restrict__ Bmats) {
    int mid = blockIdx.x;
    int layer = mid / 26, m = mid % 26;
    const float* src;
    if (m == 0)      src = Wup_s  + (size_t)layer * 4096;
    else if (m == 1) src = Wup_v  + (size_t)layer * 4096;
    else if (m == 2) src = Wout_s + (size_t)layer * 4096;
    else if (m == 3) src = Wout_v + (size_t)layer * 4096;
    else if (m == 4) src = Wprod_s + (size_t)layer * 4096;
    else if (m == 5) src = Wprod_v + (size_t)layer * 4096;
    else if (m < 16) src = Wsc_s + (size_t)layer * 40960 + (size_t)(m - 6) * 4096;
    else             src = Wsc_v + (size_t)layer * 40960 + (size_t)(m - 16) * 4096;
    _Float16* dst = Bmats + (size_t)mid * 4096;
    int lane = threadIdx.x, quad = lane >> 4, colx = lane & 15;
    for (int t = 0; t < 8; t++) {
        int kt = t >> 2, nt = t & 3;
        #pragma unroll
        for (int j = 0; j < 8; j++) {
            int k = kt * 32 + quad * 8 + j, n = nt * 16 + colx;
            dst[(size_t)t * 512 + lane * 8 + j] = (_Float16)src[k * 64 + n];
        }
    }
}

// helper: load A-frag (8 ch of one node) from planar fp32, fp16-convert
__device__ __forceinline__ half8 loadA(const float* __restrict__ base) {
    half8 a;
    float4 f0 = ((const float4*)base)[0];
    float4 f1 = ((const float4*)base)[1];
    a[0]=(_Float16)f0.x; a[1]=(_Float16)f0.y; a[2]=(_Float16)f0.z; a[3]=(_Float16)f0.w;
    a[4]=(_Float16)f1.x; a[5]=(_Float16)f1.y; a[6]=(_Float16)f1.z; a[7]=(_Float16)f1.w;
    return a;
}

// helper: load 4 A-frags (8 ch, 4 components) from fp16-packed half4 stream
__device__ __forceinline__ void loadAgg4(const float2* __restrict__ base,
                                         half8* a0, half8* a1, half8* a2, half8* a3) {
    #pragma unroll
    for (int j = 0; j < 8; j++) {
        float2 p = base[j];
        F2H u1, u2; u1.f = p.x; u2.f = p.y;
        (*a0)[j] = u1.h[0]; (*a1)[j] = u1.h[1];
        (*a2)[j] = u2.h[0]; (*a3)[j] = u2.h[1];
    }
}

// ---- node kernel A: up-projection (fp16 pack) + species skip (fp16 scph) ----
// All tiles species-uniform (padded sort) -> branch-free MFMA.
__global__ __launch_bounds__(256, 4)
void k_nodeA(const float* __restrict__ s, const float* __restrict__ v,
             const int* __restrict__ species,
             const _Float16* __restrict__ Bup_s, const _Float16* __restrict__ Bup_v,
             const _Float16* __restrict__ Bsc_s, const _Float16* __restrict__ Bsc_v,
             float2* __restrict__ packh, float2* __restrict__ scph, int Npad) {
    const int tid = threadIdx.x;
    const int lane = tid & 63, wave = tid >> 6;
    const int quad = lane >> 4, col = lane & 15;
    const int n0 = blockIdx.x * 64 + wave * 16;
    if (n0 >= Npad) return;

    half8 as[2], av0[2], av1[2], av2[2];
    int node = n0 + col;
    const float* sp = s + (size_t)node * 64;
    const float* vp = v + (size_t)node * 192;
    #pragma unroll
    for (int kt = 0; kt < 2; kt++) {
        int kb = kt * 32 + quad * 8;
        as[kt]  = loadA(sp + kb);
        av0[kt] = loadA(vp + kb);
        av1[kt] = loadA(vp + 64 + kb);
        av2[kt] = loadA(vp + 128 + kb);
    }

    const int z = species[n0];
    const _Float16* Bs = Bsc_s + (size_t)z * 4096;
    const _Float16* Bv = Bsc_v + (size_t)z * 4096;

    #pragma unroll
    for (int nt = 0; nt < 4; nt++) {
        // up-projection
        floatx4 cs = {0,0,0,0}, c0 = {0,0,0,0}, c1 = {0,0,0,0}, c2 = {0,0,0,0};
        // species skip
        floatx4 ds = {0,0,0,0}, d0 = {0,0,0,0}, d1 = {0,0,0,0}, d2 = {0,0,0,0};
        #pragma unroll
        for (int kt = 0; kt < 2; kt++) {
            half8 bs = *(const half8*)(Bup_s + (((size_t)kt * 4 + nt) * 64 + lane) * 8);
            half8 bv = *(const half8*)(Bup_v + (((size_t)kt * 4 + nt) * 64 + lane) * 8);
            half8 es = *(const half8*)(Bs + (((size_t)kt * 4 + nt) * 64 + lane) * 8);
            half8 ev = *(const half8*)(Bv + (((size_t)kt * 4 + nt) * 64 + lane) * 8);
            cs = __builtin_amdgcn_mfma_f32_16x16x32_f16(as[kt],  bs, cs, 0, 0, 0);
            c0 = __builtin_amdgcn_mfma_f32_16x16x32_f16(av0[kt], bv, c0, 0, 0, 0);
            c1 = __builtin_amdgcn_mfma_f32_16x16x32_f16(av1[kt], bv, c1, 0, 0, 0);
            c2 = __builtin_amdgcn_mfma_f32_16x16x32_f16(av2[kt], bv, c2, 0, 0, 0);
            ds = __builtin_amdgcn_mfma_f32_16x16x32_f16(as[kt],  es, ds, 0, 0, 0);
            d0 = __builtin_amdgcn_mfma_f32_16x16x32_f16(av0[kt], ev, d0, 0, 0, 0);
            d1 = __builtin_amdgcn_mfma_f32_16x16x32_f16(av1[kt], ev, d1, 0, 0, 0);
            d2 = __builtin_amdgcn_mfma_f32_16x16x32_f16(av2[kt], ev, d2, 0, 0, 0);
        }
        int ch = nt * 16 + col;
        #pragma unroll
        for (int r = 0; r < 4; r++) {
            int n = n0 + quad * 4 + r;
            F2H u1, u2, w1, w2;
            u1.h[0] = (_Float16)cs[r]; u1.h[1] = (_Float16)c0[r];
            u2.h[0] = (_Float16)c1[r]; u2.h[1] = (_Float16)c2[r];
            w1.h[0] = (_Float16)ds[r]; w1.h[1] = (_Float16)d0[r];
            w2.h[0] = (_Float16)d1[r]; w2.h[1] = (_Float16)d2[r];
            packh[(size_t)n * 64 + ch] = make_float2(u1.f, u2.f);
            scph[(size_t)n * 64 + ch]  = make_float2(w1.f, w2.f);
        }
    }
}

// ---- message kernel: MFMA edge-MLP, fp16 inputs, hoisted gathers, nt msg stores ----
#define ROWP 72
__global__ __launch_bounds__(256, 4)
void k_msg(const int* __restrict__ rowptr, int na, int nb,
           const _Float16* __restrict__ efh, const float4* __restrict__ geo,
           const int* __restrict__ snd_s, const float2* __restrict__ packh,
           const _Float16* __restrict__ B1f, const _Float16* __restrict__ B2f,
           const _Float16* __restrict__ B3f, float2* __restrict__ msg,
           int cap, int E) {
    __shared__ _Float16 a2[4 * 16 * ROWP];
    __shared__ _Float16 a3[4 * 16 * ROWP];
    const int tid = threadIdx.x;
    const int lane = tid & 63;
    const int wave = tid >> 6;
    const int quad = lane >> 4;
    const int col = lane & 15;
    const int Jlo = rowptr[na], Jhi = rowptr[nb];
    const int j0 = Jlo + blockIdx.x * 64 + wave * 16;

    _Float16* a2w = a2 + wave * 16 * ROWP;
    _Float16* a3w = a3 + wave * 16 * ROWP;

    // ---- stage 1: h1 = silu(ef @ RW1) (K padded 8->32); ef = one 16B load ----
    half8 aef;
    #pragma unroll
    for (int k = 0; k < 8; k++) aef[k] = (_Float16)0.0f;
    {
        int je = j0 + col;
        if (quad == 0 && je < Jhi)
            aef = *(const half8*)(efh + (size_t)je * 8);
    }
    {
        floatx4 c1[4];
        #pragma unroll
        for (int nt = 0; nt < 4; nt++) {
            c1[nt] = (floatx4){0.0f, 0.0f, 0.0f, 0.0f};
            half8 b = *(const half8*)(B1f + ((size_t)nt * 64 + lane) * 8);
            c1[nt] = __builtin_amdgcn_mfma_f32_16x16x32_f16(aef, b, c1[nt], 0, 0, 0);
        }
        #pragma unroll
        for (int nt = 0; nt < 4; nt++)
            #pragma unroll
            for (int r = 0; r < 4; r++)
                a2w[(quad * 4 + r) * ROWP + nt * 16 + col] = (_Float16)siluf(c1[nt][r]);
    }
    __syncthreads();

    // ---- stage 2: h2 = silu(h1 @ RW2) ----
    {
        half8 af0 = *(const half8*)&a2w[col * ROWP + quad * 8];
        half8 af1 = *(const half8*)&a2w[col * ROWP + 32 + quad * 8];
        floatx4 c2[4];
        #pragma unroll
        for (int nt = 0; nt < 4; nt++) {
            c2[nt] = (floatx4){0.0f, 0.0f, 0.0f, 0.0f};
            half8 b0 = *(const half8*)(B2f + (((size_t)0 * 4 + nt) * 64 + lane) * 8);
            half8 b1 = *(const half8*)(B2f + (((size_t)1 * 4 + nt) * 64 + lane) * 8);
            c2[nt] = __builtin_amdgcn_mfma_f32_16x16x32_f16(af0, b0, c2[nt], 0, 0, 0);
            c2[nt] = __builtin_amdgcn_mfma_f32_16x16x32_f16(af1, b1, c2[nt], 0, 0, 0);
        }
        #pragma unroll
        for (int nt = 0; nt < 4; nt++)
            #pragma unroll
            for (int r = 0; r < 4; r++)
                a3w[(quad * 4 + r) * ROWP + nt * 16 + col] = (_Float16)siluf(c2[nt][r]);
    }
    __syncthreads();

    // ---- stage 3: hoisted per-edge gathers + w = h2 @ RW3 + message epilogue ----
    const float inv32 = 1.0f / 32.0f;
    const float is3 = 0.5773502691896258f;
    const float is2 = 0.7071067811865476f;
    half8 a3f0 = *(const half8*)&a3w[col * ROWP + quad * 8];
    half8 a3f1 = *(const half8*)&a3w[col * ROWP + 32 + quad * 8];

    int sndr[4];
    float4 gr[4];
    #pragma unroll
    for (int r = 0; r < 4; r++) {
        int jj = j0 + quad * 4 + r;
        if (jj < Jhi && (jj - Jlo) < cap) {
            sndr[r] = snd_s[jj];
            gr[r] = geo[jj];
        } else {
            sndr[r] = -1;
            gr[r] = make_float4(0.0f, 0.0f, 0.0f, 0.0f);
        }
    }

    for (int cb = 0; cb < 4; cb++) {
        floatx4 acc[5];
        #pragma unroll
        for (int q = 0; q < 5; q++) {
            acc[q] = (floatx4){0.0f, 0.0f, 0.0f, 0.0f};
            int nt = q * 4 + cb;
            half8 b0 = *(const half8*)(B3f + (((size_t)0 * 20 + nt) * 64 + lane) * 8);
            half8 b1 = *(const half8*)(B3f + (((size_t)1 * 20 + nt) * 64 + lane) * 8);
            acc[q] = __builtin_amdgcn_mfma_f32_16x16x32_f16(a3f0, b0, acc[q], 0, 0, 0);
            acc[q] = __builtin_amdgcn_mfma_f32_16x16x32_f16(a3f1, b1, acc[q], 0, 0, 0);
        }
        const int c = cb * 16 + col;
        #pragma unroll
        for (int r = 0; r < 4; r++) {
            if (sndr[r] >= 0) {
                int idx = j0 + quad * 4 + r - Jlo;
                float4 g = gr[r];
                float2 pp = packh[(size_t)sndr[r] * 64 + c];
                F2H u1, u2; u1.f = pp.x; u2.f = pp.y;
                float pvx = (float)u1.h[0], pvy = (float)u1.h[1];
                float pvz = (float)u2.h[0], pvw = (float)u2.h[1];
                float w00 = acc[0][r], w110 = acc[1][r], w011 = acc[2][r];
                float w101 = acc[3][r], w111 = acc[4][r];
                float dvy = pvy * g.x + pvz * g.y + pvw * g.z;
                float m0 = (w00 * pvx + w110 * dvy * is3) * inv32;
                float cxv = pvz * g.z - pvw * g.y;
                float cyv = pvw * g.x - pvy * g.z;
                float czv = pvy * g.y - pvz * g.x;
                float m1x = (w011 * pvx * g.x + w101 * pvy + w111 * cxv * is2) * inv32;
                float m1y = (w011 * pvx * g.y + w101 * pvz + w111 * cyv * is2) * inv32;
                float m1z = (w011 * pvx * g.z + w101 * pvw + w111 * czv * is2) * inv32;
                D2F2 o;
                F2H o1, o2;
                o1.h[0] = (_Float16)m0;  o1.h[1] = (_Float16)m1x;
                o2.h[0] = (_Float16)m1y; o2.h[1] = (_Float16)m1z;
                o.v = make_float2(o1.f, o2.f);
                __builtin_nontemporal_store(o.d, (double*)&msg[(size_t)idx * 64 + c]);
            }
        }
    }
}

// ---------------- CSR aggregation: wave per node, lane = channel; fp16 out ----------
__global__ void k_agg(const float2* __restrict__ msg, const int* __restrict__ rowptr,
                      float2* __restrict__ aggh, int na, int nb, int cap) {
    int n = na + blockIdx.x * 4 + (threadIdx.x >> 6);
    int lane = threadIdx.x & 63;
    if (n >= nb) return;
    int Jlo = rowptr[na];
    int j0 = rowptr[n], j1 = rowptr[n + 1];
    float a0 = 0.0f, a1 = 0.0f, a2 = 0.0f, a3 = 0.0f;
    for (int j = j0; j < j1; j++) {
        int idx = j - Jlo;
        if (idx >= cap) break;
        D2F2 m;
        m.d = __builtin_nontemporal_load((const double*)&msg[(size_t)idx * 64 + lane]);
        F2H u1, u2; u1.f = m.v.x; u2.f = m.v.y;
        a0 += (float)u1.h[0]; a1 += (float)u1.h[1];
        a2 += (float)u2.h[0]; a3 += (float)u2.h[1];
    }
    F2H o1, o2;
    o1.h[0] = (_Float16)a0; o1.h[1] = (_Float16)a1;
    o2.h[0] = (_Float16)a2; o2.h[1] = (_Float16)a3;
    aggh[(size_t)n * 64 + lane] = make_float2(o1.f, o2.f);
}

// ---- node kernel B: Wout MFMA -> P0/P1 epilogue -> LDS transpose -> Wprod MFMA -----
#define ROWPB 72
__global__ __launch_bounds__(256, 4)
void k_nodeB(const float2* __restrict__ aggh,
             const int* __restrict__ species, const int* __restrict__ origid,
             const _Float16* __restrict__ Bout_s, const _Float16* __restrict__ Bout_v,
             const _Float16* __restrict__ Bprod_s, const _Float16* __restrict__ Bprod_v,
             const float* __restrict__ P0l, const float* __restrict__ P1l,
             const float2* __restrict__ scph, float* __restrict__ s,
             float* __restrict__ v, float* __restrict__ out,
             int Npad, int layer, int Ltot) {
    __shared__ _Float16 lds[4 * 4 * 16 * ROWPB];
    const int tid = threadIdx.x;
    const int lane = tid & 63, wave = tid >> 6;
    const int quad = lane >> 4, col = lane & 15;
    const int n0 = blockIdx.x * 64 + wave * 16;
    if (n0 >= Npad) return;   // all waves of a block share fate (Npad multiple of 64)
    _Float16* lw = lds + wave * 4 * 16 * ROWPB;

    const int z = species[n0];   // tile-uniform (padded sort)
    {
        half8 as[2], av0[2], av1[2], av2[2];
        int node = n0 + col;
        const float2* ab = aggh + (size_t)node * 64;
        #pragma unroll
        for (int kt = 0; kt < 2; kt++) {
            int kb = kt * 32 + quad * 8;
            loadAgg4(ab + kb, &as[kt], &av0[kt], &av1[kt], &av2[kt]);
        }
        #pragma unroll
        for (int nt = 0; nt < 4; nt++) {
            floatx4 cs = {0,0,0,0}, c0 = {0,0,0,0}, c1 = {0,0,0,0}, c2 = {0,0,0,0};
            #pragma unroll
            for (int kt = 0; kt < 2; kt++) {
                half8 bs = *(const half8*)(Bout_s + (((size_t)kt * 4 + nt) * 64 + lane) * 8);
                half8 bv = *(const half8*)(Bout_v + (((size_t)kt * 4 + nt) * 64 + lane) * 8);
                cs = __builtin_amdgcn_mfma_f32_16x16x32_f16(as[kt],  bs, cs, 0, 0, 0);
                c0 = __builtin_amdgcn_mfma_f32_16x16x32_f16(av0[kt], bv, c0, 0, 0, 0);
                c1 = __builtin_amdgcn_mfma_f32_16x16x32_f16(av1[kt], bv, c1, 0, 0, 0);
                c2 = __builtin_amdgcn_mfma_f32_16x16x32_f16(av2[kt], bv, c2, 0, 0, 0);
            }
            int ch = nt * 16 + col;
            const float* p = P0l + ((size_t)z * 64 + ch) * 3;
            const float* q = P1l + ((size_t)z * 64 + ch) * 2;
            float p0 = p[0], p1 = p[1], p2 = p[2];
            float q0 = q[0], q1 = q[1];
            #pragma unroll
            for (int r = 0; r < 4; r++) {
                int nl = quad * 4 + r;
                float msv = cs[r];
                float m0 = c0[r], m1 = c1[r], m2 = c2[r];
                float ps = p0 * msv + p1 * msv * msv + p2 * (m0 * m0 + m1 * m1 + m2 * m2);
                float qq = q0 + q1 * msv;
                lw[0 * 16 * ROWPB + nl * ROWPB + ch] = (_Float16)ps;
                lw[1 * 16 * ROWPB + nl * ROWPB + ch] = (_Float16)(qq * m0);
                lw[2 * 16 * ROWPB + nl * ROWPB + ch] = (_Float16)(qq * m1);
                lw[3 * 16 * ROWPB + nl * ROWPB + ch] = (_Float16)(qq * m2);
            }
        }
    }
    __syncthreads();
    {
        half8 as[2], av0[2], av1[2], av2[2];
        #pragma unroll
        for (int kt = 0; kt < 2; kt++) {
            int kb = kt * 32 + quad * 8;
            as[kt]  = *(const half8*)&lw[0 * 16 * ROWPB + col * ROWPB + kb];
            av0[kt] = *(const half8*)&lw[1 * 16 * ROWPB + col * ROWPB + kb];
            av1[kt] = *(const half8*)&lw[2 * 16 * ROWPB + col * ROWPB + kb];
            av2[kt] = *(const half8*)&lw[3 * 16 * ROWPB + col * ROWPB + kb];
        }
        int og[4];
        #pragma unroll
        for (int r = 0; r < 4; r++) og[r] = origid[n0 + quad * 4 + r];
        #pragma unroll
        for (int nt = 0; nt < 4; nt++) {
            floatx4 cs = {0,0,0,0}, c0 = {0,0,0,0}, c1 = {0,0,0,0}, c2 = {0,0,0,0};
            #pragma unroll
            for (int kt = 0; kt < 2; kt++) {
                half8 bs = *(const half8*)(Bprod_s + (((size_t)kt * 4 + nt) * 64 + lane) * 8);
                half8 bv = *(const half8*)(Bprod_v + (((size_t)kt * 4 + nt) * 64 + lane) * 8);
                cs = __builtin_amdgcn_mfma_f32_16x16x32_f16(as[kt],  bs, cs, 0, 0, 0);
                c0 = __builtin_amdgcn_mfma_f32_16x16x32_f16(av0[kt], bv, c0, 0, 0, 0);
                c1 = __builtin_amdgcn_mfma_f32_16x16x32_f16(av1[kt], bv, c1, 0, 0, 0);
                c2 = __builtin_amdgcn_mfma_f32_16x16x32_f16(av2[kt], bv, c2, 0, 0, 0);
            }
            int ch = nt * 16 + col;
            #pragma unroll
            for (int r = 0; r < 4; r++) {
                int n = n0 + quad * 4 + r;
                float2 scv = scph[(size_t)n * 64 + ch];
                F2H u1, u2; u1.f = scv.x; u2.f = scv.y;
                float sval = cs[r] + (float)u1.h[0];
                s[(size_t)n * 64 + ch] = sval;
                v[(size_t)n * 192 + ch] = c0[r] + (float)u1.h[1];
                v[(size_t)n * 192 + 64 + ch] = c1[r] + (float)u2.h[0];
                v[(size_t)n * 192 + 128 + ch] = c2[r] + (float)u2.h[1];
                if (og[r] >= 0)
                    out[(size_t)og[r] * (Ltot * 64) + layer * 64 + ch] = sval;
            }
        }
    }
}

extern "C" void kernel_launch(void* const* d_in, const int* in_sizes, int n_in,
                              void* d_out, int out_size, void* d_ws, size_t ws_size,
                              hipStream_t stream) {
    const float* node_attrs = (const float*)d_in[0];
    const float* atom_pos   = (const float*)d_in[1];
    const float* shifts     = (const float*)d_in[2];
    const float* W_embed    = (const float*)d_in[3];
    const float* Wup_s      = (const float*)d_in[4];
    const float* Wup_v      = (const float*)d_in[5];
    const float* RW1        = (const float*)d_in[6];
    const float* RW2        = (const float*)d_in[7];
    const float* RW3        = (const float*)d_in[8];
    const float* Wout_s     = (const float*)d_in[9];
    const float* Wout_v     = (const float*)d_in[10];
    const float* Wsc_s      = (const float*)d_in[11];
    const float* Wsc_v      = (const float*)d_in[12];
    const float* P0         = (const float*)d_in[13];
    const float* P1         = (const float*)d_in[14];
    const float* Wprod_s    = (const float*)d_in[15];
    const float* Wprod_v    = (const float*)d_in[16];
    const int*   ei         = (const int*)d_in[17];

    const int N = in_sizes[0] / 10;
    const int E = in_sizes[17] / 2;
    const int L = in_sizes[4] / 4096;
    const int Npad = ((N + 160) + 63) / 64 * 64;   // species-padded, 64-aligned
    float* out = (float*)d_out;

    char* wsb = (char*)d_ws;
    size_t off = 0;
    auto alloci = [&](size_t n) {
        int* p = (int*)(wsb + off);
        off = (off + n * 4 + 255) / 256 * 256;
        return p;
    };
    auto allocf = [&](size_t n) {
        float* p = (float*)(wsb + off);
        off = (off + n * 4 + 255) / 256 * 256;
        return p;
    };
    auto alloch = [&](size_t n) {
        _Float16* p = (_Float16*)(wsb + off);
        off = (off + n * 2 + 255) / 256 * 256;
        return p;
    };
    int* species_o = alloci(N);
    int* species_s = alloci(Npad);
    int* zcount    = alloci(16);
    int* zcur      = alloci(16);
    int* zstart    = alloci(16);
    int* perm_n    = alloci(Npad);
    int* inv_n     = alloci(N);
    int* origid    = alloci(Npad);
    int* deg       = alloci(Npad);
    int* rowptr    = alloci(Npad + 1);
    int* cursor    = alloci(Npad);
    int* perm      = alloci(E);
    int* snd_s     = alloci(E);
    float* s     = allocf((size_t)Npad * 64);
    float* v     = allocf((size_t)Npad * 192);
    float* geo   = allocf((size_t)E * 4);
    _Float16* efh = alloch((size_t)E * 8);
    float* packh = allocf((size_t)Npad * 128);
    float* scph  = allocf((size_t)Npad * 128);
    float* agghf = allocf((size_t)Npad * 128);
    _Float16* B1f   = alloch((size_t)L * 2048);
    _Float16* B2f   = alloch((size_t)L * 4096);
    _Float16* B3f   = alloch((size_t)L * 20480);
    _Float16* Bmats = alloch((size_t)L * 26 * 4096);

    int NCHUNK = 16;
    int cap = 0;
    {
        const int cands[8] = {1, 2, 3, 4, 6, 8, 12, 16};
        for (int ci = 0; ci < 8; ci++) {
            int c = cands[ci];
            int thiscap = (c == 1) ? E : (E / c) * 5 / 4 + 256;
            size_t need = off + (size_t)thiscap * 512;
            if (need <= ws_size) { NCHUNK = c; cap = thiscap; break; }
        }
        if (cap == 0) { NCHUNK = 16; cap = (E / 16) * 5 / 4 + 256; }
    }
    float* msg = allocf((size_t)cap * 128);
    (void)n_in; (void)out_size;

    const int NT = Npad / 64;
    const int NB = (N + 255) / 256;
    const int NPB = (Npad + 255) / 256;
    const int EB = (E + 255) / 256;
    const int MT = (cap + 63) / 64;

    hipMemsetAsync(zcount, 0, 16 * sizeof(int), stream);
    k_species<<<NB, 256, 0, stream>>>(node_attrs, species_o, zcount, N);
    k_zscan<<<1, 64, 0, stream>>>(zcount, zcur, zstart);
    k_zperm<<<NB, 256, 0, stream>>>(species_o, zcur, perm_n, inv_n, N);
    k_padmark<<<NPB, 256, 0, stream>>>(zstart, zcur, perm_n, deg, species_s, Npad);
    k_init<<<(Npad + 3) / 4, 256, 0, stream>>>(perm_n, species_o, W_embed, species_s,
                                               origid, s, v, Npad);
    k_hist<<<EB, 256, 0, stream>>>(ei, inv_n, deg, E);
    k_scan<<<1, 1024, 0, stream>>>(deg, rowptr, cursor, Npad);
    k_eperm<<<EB, 256, 0, stream>>>(ei, inv_n, cursor, perm, E);
    k_geom<<<EB, 256, 0, stream>>>(ei, perm, inv_n, atom_pos, shifts,
                                   (float4*)geo, efh, snd_s, E);
    k_wprep<<<52 * L, 64, 0, stream>>>(RW1, RW2, RW3, B1f, B2f, B3f);
    k_wprep_node<<<26 * L, 64, 0, stream>>>(Wup_s, Wup_v, Wout_s, Wout_v,
                                            Wprod_s, Wprod_v, Wsc_s, Wsc_v, Bmats);

    int nbound[17];
    for (int k = 0; k <= NCHUNK; k++) nbound[k] = (int)((long long)Npad * k / NCHUNK);

    for (int i = 0; i < L; i++) {
        const _Float16* Bl = Bmats + (size_t)i * 26 * 4096;
        k_nodeA<<<NT, 256, 0, stream>>>(s, v, species_s,
                                        Bl, Bl + 4096,
                                        Bl + 6 * 4096, Bl + 16 * 4096,
                                        (float2*)packh, (float2*)scph, Npad);
        for (int k = 0; k < NCHUNK; k++) {
            int na = nbound[k], nb = nbound[k + 1];
            k_msg<<<MT, 256, 0, stream>>>(rowptr, na, nb, efh, (const float4*)geo, snd_s,
                                          (const float2*)packh,
                                          B1f + (size_t)i * 2048, B2f + (size_t)i * 4096,
                                          B3f + (size_t)i * 20480, (float2*)msg, cap, E);
            int cnt = nb - na;
            k_agg<<<(cnt + 3) / 4, 256, 0, stream>>>((const float2*)msg, rowptr,
                                                     (float2*)agghf, na, nb, cap);
        }
        k_nodeB<<<NT, 256, 0, stream>>>((const float2*)agghf, species_s, origid,
                                        Bl + 2 * 4096, Bl + 3 * 4096,
                                        Bl + 4 * 4096, Bl + 5 * 4096,
                                        P0 + (size_t)i * 1920, P1 + (size_t)i * 1280,
                                        (const float2*)scph, s, v, out, Npad, i, L);
    }
}

// Round 12
// 637.036 us; speedup vs baseline: 1.2882x; 1.0114x over previous
//
#include <hip/hip_runtime.h>
#include <hip/hip_bf16.h>
#include <hip/hip_fp16.h>

typedef _Float16 half8 __attribute__((ext_vector_type(8)));
typedef float floatx4 __attribute__((ext_vector_type(4)));

union F2H { float f; _Float16 h[2]; };

__device__ __forceinline__ float siluf(float x) {
    return x / (1.0f + __expf(-x));
}

// ---------------- species per node + histogram ----------------
__global__ void k_species(const float* __restrict__ attrs, int* __restrict__ species_o,
                          int* __restrict__ zcount, int N) {
    int n = blockIdx.x * 256 + threadIdx.x;
    if (n >= N) return;
    int z = 0;
    #pragma unroll
    for (int k = 1; k < 10; k++) if (attrs[n * 10 + k] > 0.5f) z = k;
    species_o[n] = z;
    atomicAdd(&zcount[z], 1);
}

// bucket starts rounded up to 16-node tiles
__global__ void k_zscan(const int* __restrict__ zcount, int* __restrict__ zcur,
                        int* __restrict__ zstart) {
    if (threadIdx.x == 0) {
        int run = 0;
        for (int z = 0; z < 10; z++) {
            zstart[z] = run;
            zcur[z] = run;
            run += (zcount[z] + 15) & ~15;
        }
        zstart[10] = run;
    }
}

__global__ void k_zperm(const int* __restrict__ species_o, int* __restrict__ zcur,
                        int* __restrict__ perm_n, int* __restrict__ inv_n, int N) {
    int n = blockIdx.x * 256 + threadIdx.x;
    if (n >= N) return;
    int pos = atomicAdd(&zcur[species_o[n]], 1);
    perm_n[pos] = n;
    inv_n[n] = pos;
}

// mark pad slots (perm_n=-1, species filled for tile uniformity), zero deg everywhere
__global__ void k_padmark(const int* __restrict__ zstart, const int* __restrict__ zcur,
                          int* __restrict__ perm_n, int* __restrict__ deg,
                          int* __restrict__ species_s, int Npad) {
    int p = blockIdx.x * 256 + threadIdx.x;
    if (p >= Npad) return;
    deg[p] = 0;
    if (p >= zstart[10]) {
        perm_n[p] = -1;
        species_s[p] = 9;
        return;
    }
    int z = 9;
    #pragma unroll
    for (int q = 0; q < 10; q++) {
        if (p < zstart[q + 1]) { z = q; break; }
    }
    if (p >= zcur[z]) {
        perm_n[p] = -1;
        species_s[p] = z;
    }
}

// ---------------- init state in SPECIES-SORTED (padded) node order ----------------
__global__ void k_init(const int* __restrict__ perm_n, const int* __restrict__ species_o,
                       const float* __restrict__ Wemb, int* __restrict__ species_s,
                       int* __restrict__ origid, float* __restrict__ s,
                       float* __restrict__ v, int Npad) {
    int p = blockIdx.x * 4 + (threadIdx.x >> 6);
    if (p >= Npad) return;
    int lane = threadIdx.x & 63;
    int n = perm_n[p];
    if (n < 0) {
        if (lane == 0) origid[p] = -1;
        s[(size_t)p * 64 + lane] = 0.0f;
        v[(size_t)p * 192 + lane] = 0.0f;
        v[(size_t)p * 192 + 64 + lane] = 0.0f;
        v[(size_t)p * 192 + 128 + lane] = 0.0f;
        return;
    }
    int z = species_o[n];
    if (lane == 0) { species_s[p] = z; origid[p] = n; }
    s[(size_t)p * 64 + lane] = Wemb[z * 64 + lane];
    v[(size_t)p * 192 + lane] = 0.0f;
    v[(size_t)p * 192 + 64 + lane] = 0.0f;
    v[(size_t)p * 192 + 128 + lane] = 0.0f;
}

// ---------------- counting sort of edges by (sorted) receiver ----------------
__global__ void k_hist(const int* __restrict__ ei, const int* __restrict__ inv_n,
                       int* __restrict__ deg, int E) {
    int e = blockIdx.x * 256 + threadIdx.x;
    if (e < E) atomicAdd(&deg[inv_n[ei[E + e]]], 1);
}

__global__ void k_scan(const int* __restrict__ deg, int* __restrict__ rowptr,
                       int* __restrict__ cursor, int N) {
    __shared__ int part[1024];
    int t = threadIdx.x;
    int chunk = (N + 1023) / 1024;
    int lo = t * chunk, hi = min(lo + chunk, N);
    int sum = 0;
    for (int i = lo; i < hi; i++) sum += deg[i];
    part[t] = sum;
    __syncthreads();
    for (int off = 1; off < 1024; off <<= 1) {
        int add = (t >= off) ? part[t - off] : 0;
        __syncthreads();
        part[t] += add;
        __syncthreads();
    }
    int run = (t > 0) ? part[t - 1] : 0;
    for (int i = lo; i < hi; i++) { rowptr[i] = run; cursor[i] = run; run += deg[i]; }
    if (t == 1023) rowptr[N] = part[1023];
}

__global__ void k_eperm(const int* __restrict__ ei, const int* __restrict__ inv_n,
                        int* __restrict__ cursor, int* __restrict__ perm, int E) {
    int e = blockIdx.x * 256 + threadIdx.x;
    if (e < E) {
        int r = inv_n[ei[E + e]];
        int pos = atomicAdd(&cursor[r], 1);
        perm[pos] = e;
    }
}

// ---------------- geometry + radial basis; ef in EDGE-MAJOR fp16 ----------------
__global__ void k_geom(const int* __restrict__ ei, const int* __restrict__ perm,
                       const int* __restrict__ inv_n, const float* __restrict__ pos,
                       const float* __restrict__ shifts, float4* __restrict__ geo,
                       _Float16* __restrict__ efh, int* __restrict__ snd_s,
                       int* __restrict__ rcv_s, int E) {
    int j = blockIdx.x * 256 + threadIdx.x;
    if (j >= E) return;
    int e = perm[j];
    int snd = ei[e], rcv = ei[E + e];
    float dx = pos[rcv * 3 + 0] - pos[snd * 3 + 0] + shifts[e * 3 + 0];
    float dy = pos[rcv * 3 + 1] - pos[snd * 3 + 1] + shifts[e * 3 + 1];
    float dz = pos[rcv * 3 + 2] - pos[snd * 3 + 2] + shifts[e * 3 + 2];
    float r = sqrtf(dx * dx + dy * dy + dz * dz);
    float rin = 1.0f / (r + 1e-9f);
    const float SQ3 = 1.7320508075688772f;
    geo[j] = make_float4(SQ3 * dx * rin, SQ3 * dy * rin, SQ3 * dz * rin, 0.0f);
    snd_s[j] = inv_n[snd];
    rcv_s[j] = inv_n[rcv];
    float u = r * 0.2f;
    float env = 0.0f;
    if (u < 1.0f) {
        float u2 = u * u;
        float u6 = u2 * u2 * u2;
        env = 1.0f - 28.0f * u6 + 48.0f * u6 * u - 21.0f * u6 * u2;
    }
    const float PIF = 3.14159265358979f;
    float x = PIF * u;
    float sp = __sinf(x), cp = __cosf(x);
    float coef = 0.6324555320336759f * rin * env;
    float sm1 = 0.0f, scur = sp, twoc = 2.0f * cp;
    half8 e8;
    #pragma unroll
    for (int k = 0; k < 8; k++) {
        e8[k] = (_Float16)(coef * scur);
        float nxt = twoc * scur - sm1;
        sm1 = scur; scur = nxt;
    }
    *(half8*)(efh + (size_t)j * 8) = e8;
}

// -------- weight prep (edge MLP): RW1/RW2/RW3 -> fp16 B-frag (16x16x32 MFMA) --------
__global__ void k_wprep(const float* __restrict__ RW1, const float* __restrict__ RW2,
                        const float* __restrict__ RW3, _Float16* __restrict__ B1f,
                        _Float16* __restrict__ B2f, _Float16* __restrict__ B3f) {
    int lane = threadIdx.x;
    int t = blockIdx.x;
    int layer = t / 52;
    int tt = t % 52;
    int quad = lane >> 4, colx = lane & 15;
    if (tt < 4) {
        int nt = tt;
        const float* W = RW1 + (size_t)layer * 512;
        _Float16* dst = B1f + (size_t)layer * 2048 + ((size_t)nt * 64 + lane) * 8;
        #pragma unroll
        for (int j = 0; j < 8; j++) {
            int k = quad * 8 + j, n = nt * 16 + colx;
            dst[j] = (k < 8) ? (_Float16)W[k * 64 + n] : (_Float16)0.0f;
        }
    } else if (tt < 12) {
        int u = tt - 4;
        int kt = u >> 2, nt = u & 3;
        const float* W = RW2 + (size_t)layer * 4096;
        _Float16* dst = B2f + (size_t)layer * 4096 + (((size_t)kt * 4 + nt) * 64 + lane) * 8;
        #pragma unroll
        for (int j = 0; j < 8; j++) {
            int k = kt * 32 + quad * 8 + j, n = nt * 16 + colx;
            dst[j] = (_Float16)W[k * 64 + n];
        }
    } else {
        int u = tt - 12;
        int kt = u / 20, nt = u % 20;
        const float* W = RW3 + (size_t)layer * 20480;
        _Float16* dst = B3f + (size_t)layer * 20480 + (((size_t)kt * 20 + nt) * 64 + lane) * 8;
        #pragma unroll
        for (int j = 0; j < 8; j++) {
            int k = kt * 32 + quad * 8 + j, n = nt * 16 + colx;
            dst[j] = (_Float16)W[k * 320 + n];
        }
    }
}

// -------- weight prep (node mats): 64x64 fp32 -> B-frag fp16. 26 mats per layer -----
__global__ void k_wprep_node(const float* __restrict__ Wup_s, const float* __restrict__ Wup_v,
                             const float* __restrict__ Wout_s, const float* __restrict__ Wout_v,
                             const float* __restrict__ Wprod_s, const float* __restrict__ Wprod_v,
                             const float* __restrict__ Wsc_s, const float* __restrict__ Wsc_v,
                             _Float16* __restrict__ Bmats) {
    int mid = blockIdx.x;
    int layer = mid / 26, m = mid % 26;
    const float* src;
    if (m == 0)      src = Wup_s  + (size_t)layer * 4096;
    else if (m == 1) src = Wup_v  + (size_t)layer * 4096;
    else if (m == 2) src = Wout_s + (size_t)layer * 4096;
    else if (m == 3) src = Wout_v + (size_t)layer * 4096;
    else if (m == 4) src = Wprod_s + (size_t)layer * 4096;
    else if (m == 5) src = Wprod_v + (size_t)layer * 4096;
    else if (m < 16) src = Wsc_s + (size_t)layer * 40960 + (size_t)(m - 6) * 4096;
    else             src = Wsc_v + (size_t)layer * 40960 + (size_t)(m - 16) * 4096;
    _Float16* dst = Bmats + (size_t)mid * 4096;
    int lane = threadIdx.x, quad = lane >> 4, colx = lane & 15;
    for (int t = 0; t < 8; t++) {
        int kt = t >> 2, nt = t & 3;
        #pragma unroll
        for (int j = 0; j < 8; j++) {
            int k = kt * 32 + quad * 8 + j, n = nt * 16 + colx;
            dst[(size_t)t * 512 + lane * 8 + j] = (_Float16)src[k * 64 + n];
        }
    }
}

// helper: load A-frag (8 ch of one node) from planar fp32, fp16-convert
__device__ __forceinline__ half8 loadA(const float* __restrict__ base) {
    half8 a;
    float4 f0 = ((const float4*)base)[0];
    float4 f1 = ((const float4*)base)[1];
    a[0]=(_Float16)f0.x; a[1]=(_Float16)f0.y; a[2]=(_Float16)f0.z; a[3]=(_Float16)f0.w;
    a[4]=(_Float16)f1.x; a[5]=(_Float16)f1.y; a[6]=(_Float16)f1.z; a[7]=(_Float16)f1.w;
    return a;
}

// ---- node kernel A: up-projection (fp16 pack) + species skip (fp16 scph) + agg=0 ----
__global__ __launch_bounds__(256, 4)
void k_nodeA(const float* __restrict__ s, const float* __restrict__ v,
             const int* __restrict__ species,
             const _Float16* __restrict__ Bup_s, const _Float16* __restrict__ Bup_v,
             const _Float16* __restrict__ Bsc_s, const _Float16* __restrict__ Bsc_v,
             float2* __restrict__ packh, float2* __restrict__ scph,
             float* __restrict__ agg0, float* __restrict__ agg1, int Npad) {
    const int tid = threadIdx.x;
    const int lane = tid & 63, wave = tid >> 6;
    const int quad = lane >> 4, col = lane & 15;
    const int n0 = blockIdx.x * 64 + wave * 16;
    if (n0 >= Npad) return;

    half8 as[2], av0[2], av1[2], av2[2];
    int node = n0 + col;
    const float* sp = s + (size_t)node * 64;
    const float* vp = v + (size_t)node * 192;
    #pragma unroll
    for (int kt = 0; kt < 2; kt++) {
        int kb = kt * 32 + quad * 8;
        as[kt]  = loadA(sp + kb);
        av0[kt] = loadA(vp + kb);
        av1[kt] = loadA(vp + 64 + kb);
        av2[kt] = loadA(vp + 128 + kb);
    }

    const int z = species[n0];
    const _Float16* Bs = Bsc_s + (size_t)z * 4096;
    const _Float16* Bv = Bsc_v + (size_t)z * 4096;

    #pragma unroll
    for (int nt = 0; nt < 4; nt++) {
        floatx4 cs = {0,0,0,0}, c0 = {0,0,0,0}, c1 = {0,0,0,0}, c2 = {0,0,0,0};
        floatx4 ds = {0,0,0,0}, d0 = {0,0,0,0}, d1 = {0,0,0,0}, d2 = {0,0,0,0};
        #pragma unroll
        for (int kt = 0; kt < 2; kt++) {
            half8 bs = *(const half8*)(Bup_s + (((size_t)kt * 4 + nt) * 64 + lane) * 8);
            half8 bv = *(const half8*)(Bup_v + (((size_t)kt * 4 + nt) * 64 + lane) * 8);
            half8 es = *(const half8*)(Bs + (((size_t)kt * 4 + nt) * 64 + lane) * 8);
            half8 ev = *(const half8*)(Bv + (((size_t)kt * 4 + nt) * 64 + lane) * 8);
            cs = __builtin_amdgcn_mfma_f32_16x16x32_f16(as[kt],  bs, cs, 0, 0, 0);
            c0 = __builtin_amdgcn_mfma_f32_16x16x32_f16(av0[kt], bv, c0, 0, 0, 0);
            c1 = __builtin_amdgcn_mfma_f32_16x16x32_f16(av1[kt], bv, c1, 0, 0, 0);
            c2 = __builtin_amdgcn_mfma_f32_16x16x32_f16(av2[kt], bv, c2, 0, 0, 0);
            ds = __builtin_amdgcn_mfma_f32_16x16x32_f16(as[kt],  es, ds, 0, 0, 0);
            d0 = __builtin_amdgcn_mfma_f32_16x16x32_f16(av0[kt], ev, d0, 0, 0, 0);
            d1 = __builtin_amdgcn_mfma_f32_16x16x32_f16(av1[kt], ev, d1, 0, 0, 0);
            d2 = __builtin_amdgcn_mfma_f32_16x16x32_f16(av2[kt], ev, d2, 0, 0, 0);
        }
        int ch = nt * 16 + col;
        #pragma unroll
        for (int r = 0; r < 4; r++) {
            int n = n0 + quad * 4 + r;
            F2H u1, u2, w1, w2;
            u1.h[0] = (_Float16)cs[r]; u1.h[1] = (_Float16)c0[r];
            u2.h[0] = (_Float16)c1[r]; u2.h[1] = (_Float16)c2[r];
            w1.h[0] = (_Float16)ds[r]; w1.h[1] = (_Float16)d0[r];
            w2.h[0] = (_Float16)d1[r]; w2.h[1] = (_Float16)d2[r];
            packh[(size_t)n * 64 + ch] = make_float2(u1.f, u2.f);
            scph[(size_t)n * 64 + ch]  = make_float2(w1.f, w2.f);
            agg0[(size_t)n * 64 + ch] = 0.0f;
            agg1[(size_t)n * 192 + ch] = 0.0f;
            agg1[(size_t)n * 192 + 64 + ch] = 0.0f;
            agg1[(size_t)n * 192 + 128 + ch] = 0.0f;
        }
    }
}

// ---- message kernel: MFMA edge-MLP + LDS message tile + WAVE-UNIFORM run reduction --
// Block = 64 receiver-sorted edges. Messages staged in LDS [64 edges][64 ch] (row
// stride 66 float2). Reduction: thread = (channel = tid&63, segment = wave); rcv_s
// loads and run-boundary branch are wave-uniform; each wave reads only its own rows.
#define ROWP 72
#define MROW 66
__global__ __launch_bounds__(256, 4)
void k_msg(const _Float16* __restrict__ efh, const float4* __restrict__ geo,
           const int* __restrict__ snd_s, const int* __restrict__ rcv_s,
           const float2* __restrict__ packh,
           const _Float16* __restrict__ B1f, const _Float16* __restrict__ B2f,
           const _Float16* __restrict__ B3f,
           float* __restrict__ agg0, float* __restrict__ agg1, int E) {
    __shared__ float2 mt[64 * MROW];             // 33792 B; a2/a3 overlay below
    _Float16* a2 = (_Float16*)mt;                // 9216 B
    _Float16* a3 = (_Float16*)mt + 4608;         // 9216 B
    const int tid = threadIdx.x;
    const int lane = tid & 63;
    const int wave = tid >> 6;
    const int quad = lane >> 4;
    const int col = lane & 15;
    const int j0 = blockIdx.x * 64 + wave * 16;

    _Float16* a2w = a2 + wave * 16 * ROWP;
    _Float16* a3w = a3 + wave * 16 * ROWP;

    // ---- stage 1: h1 = silu(ef @ RW1) (K padded 8->32); ef = one 16B load ----
    half8 aef;
    #pragma unroll
    for (int k = 0; k < 8; k++) aef[k] = (_Float16)0.0f;
    {
        int je = j0 + col;
        if (quad == 0 && je < E)
            aef = *(const half8*)(efh + (size_t)je * 8);
    }
    {
        floatx4 c1[4];
        #pragma unroll
        for (int nt = 0; nt < 4; nt++) {
            c1[nt] = (floatx4){0.0f, 0.0f, 0.0f, 0.0f};
            half8 b = *(const half8*)(B1f + ((size_t)nt * 64 + lane) * 8);
            c1[nt] = __builtin_amdgcn_mfma_f32_16x16x32_f16(aef, b, c1[nt], 0, 0, 0);
        }
        #pragma unroll
        for (int nt = 0; nt < 4; nt++)
            #pragma unroll
            for (int r = 0; r < 4; r++)
                a2w[(quad * 4 + r) * ROWP + nt * 16 + col] = (_Float16)siluf(c1[nt][r]);
    }
    __syncthreads();

    // ---- stage 2: h2 = silu(h1 @ RW2) ----
    {
        half8 af0 = *(const half8*)&a2w[col * ROWP + quad * 8];
        half8 af1 = *(const half8*)&a2w[col * ROWP + 32 + quad * 8];
        floatx4 c2[4];
        #pragma unroll
        for (int nt = 0; nt < 4; nt++) {
            c2[nt] = (floatx4){0.0f, 0.0f, 0.0f, 0.0f};
            half8 b0 = *(const half8*)(B2f + (((size_t)0 * 4 + nt) * 64 + lane) * 8);
            half8 b1 = *(const half8*)(B2f + (((size_t)1 * 4 + nt) * 64 + lane) * 8);
            c2[nt] = __builtin_amdgcn_mfma_f32_16x16x32_f16(af0, b0, c2[nt], 0, 0, 0);
            c2[nt] = __builtin_amdgcn_mfma_f32_16x16x32_f16(af1, b1, c2[nt], 0, 0, 0);
        }
        #pragma unroll
        for (int nt = 0; nt < 4; nt++)
            #pragma unroll
            for (int r = 0; r < 4; r++)
                a3w[(quad * 4 + r) * ROWP + nt * 16 + col] = (_Float16)siluf(c2[nt][r]);
    }
    __syncthreads();

    const float inv32 = 1.0f / 32.0f;
    const float is3 = 0.5773502691896258f;
    const float is2 = 0.7071067811865476f;
    half8 a3f0 = *(const half8*)&a3w[col * ROWP + quad * 8];
    half8 a3f1 = *(const half8*)&a3w[col * ROWP + 32 + quad * 8];
    __syncthreads();   // all waves hold a3 in regs before mt overlays the buffer

    // ---- stage 3: w = h2 @ RW3 per 16-ch block; messages -> LDS tile ----
    for (int cb = 0; cb < 4; cb++) {
        floatx4 acc[5];
        #pragma unroll
        for (int q = 0; q < 5; q++) {
            acc[q] = (floatx4){0.0f, 0.0f, 0.0f, 0.0f};
            int nt = q * 4 + cb;
            half8 b0 = *(const half8*)(B3f + (((size_t)0 * 20 + nt) * 64 + lane) * 8);
            half8 b1 = *(const half8*)(B3f + (((size_t)1 * 20 + nt) * 64 + lane) * 8);
            acc[q] = __builtin_amdgcn_mfma_f32_16x16x32_f16(a3f0, b0, acc[q], 0, 0, 0);
            acc[q] = __builtin_amdgcn_mfma_f32_16x16x32_f16(a3f1, b1, acc[q], 0, 0, 0);
        }
        const int c = cb * 16 + col;
        #pragma unroll
        for (int r = 0; r < 4; r++) {
            int m = quad * 4 + r;
            int jj = j0 + m;
            if (jj < E) {
                int snd = snd_s[jj];
                float4 g = geo[jj];
                float2 pp = packh[(size_t)snd * 64 + c];
                F2H u1, u2; u1.f = pp.x; u2.f = pp.y;
                float pvx = (float)u1.h[0], pvy = (float)u1.h[1];
                float pvz = (float)u2.h[0], pvw = (float)u2.h[1];
                float w00 = acc[0][r], w110 = acc[1][r], w011 = acc[2][r];
                float w101 = acc[3][r], w111 = acc[4][r];
                float dvy = pvy * g.x + pvz * g.y + pvw * g.z;
                float m0 = (w00 * pvx + w110 * dvy * is3) * inv32;
                float cxv = pvz * g.z - pvw * g.y;
                float cyv = pvw * g.x - pvy * g.z;
                float czv = pvy * g.y - pvz * g.x;
                float m1x = (w011 * pvx * g.x + w101 * pvy + w111 * cxv * is2) * inv32;
                float m1y = (w011 * pvx * g.y + w101 * pvz + w111 * cyv * is2) * inv32;
                float m1z = (w011 * pvx * g.z + w101 * pvw + w111 * czv * is2) * inv32;
                F2H o1, o2;
                o1.h[0] = (_Float16)m0;  o1.h[1] = (_Float16)m1x;
                o2.h[0] = (_Float16)m1y; o2.h[1] = (_Float16)m1z;
                mt[(wave * 16 + m % 16) * MROW + c] = make_float2(o1.f, o2.f);
            }
        }
    }
    // no barrier: each wave reads only rows it wrote (rows wave*16 .. wave*16+15)

    // ---- reduction: thread = (channel, wave-segment); wave-uniform run scan ----
    {
        const int c = lane;              // channel 0..63
        const int jb = blockIdx.x * 64 + wave * 16;
        float a0 = 0.0f, a1 = 0.0f, a2v = 0.0f, a3v = 0.0f;
        int prev = -1;
        for (int i = 0; i < 16; i++) {
            int j = jb + i;
            if (j >= E) break;           // wave-uniform
            int rr = rcv_s[j];           // wave-uniform scalar load
            float2 mv = mt[(wave * 16 + i) * MROW + c];
            F2H u1, u2; u1.f = mv.x; u2.f = mv.y;
            float m0 = (float)u1.h[0], m1 = (float)u1.h[1];
            float m2 = (float)u2.h[0], m3 = (float)u2.h[1];
            if (rr != prev) {            // wave-uniform branch
                if (prev >= 0) {
                    atomicAdd(&agg0[(size_t)prev * 64 + c], a0);
                    atomicAdd(&agg1[(size_t)prev * 192 + c], a1);
                    atomicAdd(&agg1[(size_t)prev * 192 + 64 + c], a2v);
                    atomicAdd(&agg1[(size_t)prev * 192 + 128 + c], a3v);
                }
                a0 = m0; a1 = m1; a2v = m2; a3v = m3;
                prev = rr;
            } else {
                a0 += m0; a1 += m1; a2v += m2; a3v += m3;
            }
        }
        if (prev >= 0) {
            atomicAdd(&agg0[(size_t)prev * 64 + c], a0);
            atomicAdd(&agg1[(size_t)prev * 192 + c], a1);
            atomicAdd(&agg1[(size_t)prev * 192 + 64 + c], a2v);
            atomicAdd(&agg1[(size_t)prev * 192 + 128 + c], a3v);
        }
    }
}

// ---- node kernel B: Wout MFMA -> P0/P1 epilogue -> LDS transpose -> Wprod MFMA -----
#define ROWPB 72
__global__ __launch_bounds__(256, 4)
void k_nodeB(const float* __restrict__ agg0, const float* __restrict__ agg1,
             const int* __restrict__ species, const int* __restrict__ origid,
             const _Float16* __restrict__ Bout_s, const _Float16* __restrict__ Bout_v,
             const _Float16* __restrict__ Bprod_s, const _Float16* __restrict__ Bprod_v,
             const float* __restrict__ P0l, const float* __restrict__ P1l,
             const float2* __restrict__ scph, float* __restrict__ s,
             float* __restrict__ v, float* __restrict__ out,
             int Npad, int layer, int Ltot) {
    __shared__ _Float16 lds[4 * 4 * 16 * ROWPB];
    const int tid = threadIdx.x;
    const int lane = tid & 63, wave = tid >> 6;
    const int quad = lane >> 4, col = lane & 15;
    const int n0 = blockIdx.x * 64 + wave * 16;
    if (n0 >= Npad) return;
    _Float16* lw = lds + wave * 4 * 16 * ROWPB;

    const int z = species[n0];
    {
        half8 as[2], av0[2], av1[2], av2[2];
        int node = n0 + col;
        const float* ap = agg0 + (size_t)node * 64;
        const float* vp = agg1 + (size_t)node * 192;
        #pragma unroll
        for (int kt = 0; kt < 2; kt++) {
            int kb = kt * 32 + quad * 8;
            as[kt]  = loadA(ap + kb);
            av0[kt] = loadA(vp + kb);
            av1[kt] = loadA(vp + 64 + kb);
            av2[kt] = loadA(vp + 128 + kb);
        }
        #pragma unroll
        for (int nt = 0; nt < 4; nt++) {
            floatx4 cs = {0,0,0,0}, c0 = {0,0,0,0}, c1 = {0,0,0,0}, c2 = {0,0,0,0};
            #pragma unroll
            for (int kt = 0; kt < 2; kt++) {
                half8 bs = *(const half8*)(Bout_s + (((size_t)kt * 4 + nt) * 64 + lane) * 8);
                half8 bv = *(const half8*)(Bout_v + (((size_t)kt * 4 + nt) * 64 + lane) * 8);
                cs = __builtin_amdgcn_mfma_f32_16x16x32_f16(as[kt],  bs, cs, 0, 0, 0);
                c0 = __builtin_amdgcn_mfma_f32_16x16x32_f16(av0[kt], bv, c0, 0, 0, 0);
                c1 = __builtin_amdgcn_mfma_f32_16x16x32_f16(av1[kt], bv, c1, 0, 0, 0);
                c2 = __builtin_amdgcn_mfma_f32_16x16x32_f16(av2[kt], bv, c2, 0, 0, 0);
            }
            int ch = nt * 16 + col;
            const float* p = P0l + ((size_t)z * 64 + ch) * 3;
            const float* q = P1l + ((size_t)z * 64 + ch) * 2;
            float p0 = p[0], p1 = p[1], p2 = p[2];
            float q0 = q[0], q1 = q[1];
            #pragma unroll
            for (int r = 0; r < 4; r++) {
                int nl = quad * 4 + r;
                float msv = cs[r];
                float m0 = c0[r], m1 = c1[r], m2 = c2[r];
                float ps = p0 * msv + p1 * msv * msv + p2 * (m0 * m0 + m1 * m1 + m2 * m2);
                float qq = q0 + q1 * msv;
                lw[0 * 16 * ROWPB + nl * ROWPB + ch] = (_Float16)ps;
                lw[1 * 16 * ROWPB + nl * ROWPB + ch] = (_Float16)(qq * m0);
                lw[2 * 16 * ROWPB + nl * ROWPB + ch] = (_Float16)(qq * m1);
                lw[3 * 16 * ROWPB + nl * ROWPB + ch] = (_Float16)(qq * m2);
            }
        }
    }
    __syncthreads();
    {
        half8 as[2], av0[2], av1[2], av2[2];
        #pragma unroll
        for (int kt = 0; kt < 2; kt++) {
            int kb = kt * 32 + quad * 8;
            as[kt]  = *(const half8*)&lw[0 * 16 * ROWPB + col * ROWPB + kb];
            av0[kt] = *(const half8*)&lw[1 * 16 * ROWPB + col * ROWPB + kb];
            av1[kt] = *(const half8*)&lw[2 * 16 * ROWPB + col * ROWPB + kb];
            av2[kt] = *(const half8*)&lw[3 * 16 * ROWPB + col * ROWPB + kb];
        }
        int og[4];
        #pragma unroll
        for (int r = 0; r < 4; r++) og[r] = origid[n0 + quad * 4 + r];
        #pragma unroll
        for (int nt = 0; nt < 4; nt++) {
            floatx4 cs = {0,0,0,0}, c0 = {0,0,0,0}, c1 = {0,0,0,0}, c2 = {0,0,0,0};
            #pragma unroll
            for (int kt = 0; kt < 2; kt++) {
                half8 bs = *(const half8*)(Bprod_s + (((size_t)kt * 4 + nt) * 64 + lane) * 8);
                half8 bv = *(const half8*)(Bprod_v + (((size_t)kt * 4 + nt) * 64 + lane) * 8);
                cs = __builtin_amdgcn_mfma_f32_16x16x32_f16(as[kt],  bs, cs, 0, 0, 0);
                c0 = __builtin_amdgcn_mfma_f32_16x16x32_f16(av0[kt], bv, c0, 0, 0, 0);
                c1 = __builtin_amdgcn_mfma_f32_16x16x32_f16(av1[kt], bv, c1, 0, 0, 0);
                c2 = __builtin_amdgcn_mfma_f32_16x16x32_f16(av2[kt], bv, c2, 0, 0, 0);
            }
            int ch = nt * 16 + col;
            #pragma unroll
            for (int r = 0; r < 4; r++) {
                int n = n0 + quad * 4 + r;
                float2 scv = scph[(size_t)n * 64 + ch];
                F2H u1, u2; u1.f = scv.x; u2.f = scv.y;
                float sval = cs[r] + (float)u1.h[0];
                s[(size_t)n * 64 + ch] = sval;
                v[(size_t)n * 192 + ch] = c0[r] + (float)u1.h[1];
                v[(size_t)n * 192 + 64 + ch] = c1[r] + (float)u2.h[0];
                v[(size_t)n * 192 + 128 + ch] = c2[r] + (float)u2.h[1];
                if (og[r] >= 0)
                    out[(size_t)og[r] * (Ltot * 64) + layer * 64 + ch] = sval;
            }
        }
    }
}

extern "C" void kernel_launch(void* const* d_in, const int* in_sizes, int n_in,
                              void* d_out, int out_size, void* d_ws, size_t ws_size,
                              hipStream_t stream) {
    const float* node_attrs = (const float*)d_in[0];
    const float* atom_pos   = (const float*)d_in[1];
    const float* shifts     = (const float*)d_in[2];
    const float* W_embed    = (const float*)d_in[3];
    const float* Wup_s      = (const float*)d_in[4];
    const float* Wup_v      = (const float*)d_in[5];
    const float* RW1        = (const float*)d_in[6];
    const float* RW2        = (const float*)d_in[7];
    const float* RW3        = (const float*)d_in[8];
    const float* Wout_s     = (const float*)d_in[9];
    const float* Wout_v     = (const float*)d_in[10];
    const float* Wsc_s      = (const float*)d_in[11];
    const float* Wsc_v      = (const float*)d_in[12];
    const float* P0         = (const float*)d_in[13];
    const float* P1         = (const float*)d_in[14];
    const float* Wprod_s    = (const float*)d_in[15];
    const float* Wprod_v    = (const float*)d_in[16];
    const int*   ei         = (const int*)d_in[17];

    const int N = in_sizes[0] / 10;
    const int E = in_sizes[17] / 2;
    const int L = in_sizes[4] / 4096;
    const int Npad = ((N + 160) + 63) / 64 * 64;   // species-padded, 64-aligned
    float* out = (float*)d_out;

    char* wsb = (char*)d_ws;
    size_t off = 0;
    auto alloci = [&](size_t n) {
        int* p = (int*)(wsb + off);
        off = (off + n * 4 + 255) / 256 * 256;
        return p;
    };
    auto allocf = [&](size_t n) {
        float* p = (float*)(wsb + off);
        off = (off + n * 4 + 255) / 256 * 256;
        return p;
    };
    auto alloch = [&](size_t n) {
        _Float16* p = (_Float16*)(wsb + off);
        off = (off + n * 2 + 255) / 256 * 256;
        return p;
    };
    int* species_o = alloci(N);
    int* species_s = alloci(Npad);
    int* zcount    = alloci(16);
    int* zcur      = alloci(16);
    int* zstart    = alloci(16);
    int* perm_n    = alloci(Npad);
    int* inv_n     = alloci(N);
    int* origid    = alloci(Npad);
    int* deg       = alloci(Npad);
    int* rowptr    = alloci(Npad + 1);
    int* cursor    = alloci(Npad);
    int* perm      = alloci(E);
    int* snd_s     = alloci(E);
    int* rcv_s     = alloci(E);
    float* s     = allocf((size_t)Npad * 64);
    float* v     = allocf((size_t)Npad * 192);
    float* agg0  = allocf((size_t)Npad * 64);
    float* agg1  = allocf((size_t)Npad * 192);
    float* geo   = allocf((size_t)E * 4);
    _Float16* efh = alloch((size_t)E * 8);
    float* packh = allocf((size_t)Npad * 128);
    float* scph  = allocf((size_t)Npad * 128);
    _Float16* B1f   = alloch((size_t)L * 2048);
    _Float16* B2f   = alloch((size_t)L * 4096);
    _Float16* B3f   = alloch((size_t)L * 20480);
    _Float16* Bmats = alloch((size_t)L * 26 * 4096);
    (void)n_in; (void)out_size; (void)ws_size;

    const int NT = Npad / 64;
    const int NB = (N + 255) / 256;
    const int NPB = (Npad + 255) / 256;
    const int EB = (E + 255) / 256;
    const int ET64 = (E + 63) / 64;

    hipMemsetAsync(zcount, 0, 16 * sizeof(int), stream);
    k_species<<<NB, 256, 0, stream>>>(node_attrs, species_o, zcount, N);
    k_zscan<<<1, 64, 0, stream>>>(zcount, zcur, zstart);
    k_zperm<<<NB, 256, 0, stream>>>(species_o, zcur, perm_n, inv_n, N);
    k_padmark<<<NPB, 256, 0, stream>>>(zstart, zcur, perm_n, deg, species_s, Npad);
    k_init<<<(Npad + 3) / 4, 256, 0, stream>>>(perm_n, species_o, W_embed, species_s,
                                               origid, s, v, Npad);
    k_hist<<<EB, 256, 0, stream>>>(ei, inv_n, deg, E);
    k_scan<<<1, 1024, 0, stream>>>(deg, rowptr, cursor, Npad);
    k_eperm<<<EB, 256, 0, stream>>>(ei, inv_n, cursor, perm, E);
    k_geom<<<EB, 256, 0, stream>>>(ei, perm, inv_n, atom_pos, shifts,
                                   (float4*)geo, efh, snd_s, rcv_s, E);
    k_wprep<<<52 * L, 64, 0, stream>>>(RW1, RW2, RW3, B1f, B2f, B3f);
    k_wprep_node<<<26 * L, 64, 0, stream>>>(Wup_s, Wup_v, Wout_s, Wout_v,
                                            Wprod_s, Wprod_v, Wsc_s, Wsc_v, Bmats);

    for (int i = 0; i < L; i++) {
        const _Float16* Bl = Bmats + (size_t)i * 26 * 4096;
        k_nodeA<<<NT, 256, 0, stream>>>(s, v, species_s,
                                        Bl, Bl + 4096,
                                        Bl + 6 * 4096, Bl + 16 * 4096,
                                        (float2*)packh, (float2*)scph, agg0, agg1, Npad);
        k_msg<<<ET64, 256, 0, stream>>>(efh, (const float4*)geo, snd_s, rcv_s,
                                        (const float2*)packh,
                                        B1f + (size_t)i * 2048, B2f + (size_t)i * 4096,
                                        B3f + (size_t)i * 20480, agg0, agg1, E);
        k_nodeB<<<NT, 256, 0, stream>>>(agg0, agg1, species_s, origid,
                                        Bl + 2 * 4096, Bl + 3 * 4096,
                                        Bl + 4 * 4096, Bl + 5 * 4096,
                                        P0 + (size_t)i * 1920, P1 + (size_t)i * 1280,
                                        (const float2*)scph, s, v, out, Npad, i, L);
    }
}

// Round 13
// 614.809 us; speedup vs baseline: 1.3348x; 1.0362x over previous
//
#include <hip/hip_runtime.h>
#include <hip/hip_bf16.h>
#include <hip/hip_fp16.h>

typedef _Float16 half8 __attribute__((ext_vector_type(8)));
typedef float floatx4 __attribute__((ext_vector_type(4)));

union F2H { float f; _Float16 h[2]; };

__device__ __forceinline__ float siluf(float x) {
    return x / (1.0f + __expf(-x));
}

// ---------------- species per node + histogram ----------------
__global__ void k_species(const float* __restrict__ attrs, int* __restrict__ species_o,
                          int* __restrict__ zcount, int N) {
    int n = blockIdx.x * 256 + threadIdx.x;
    if (n >= N) return;
    int z = 0;
    #pragma unroll
    for (int k = 1; k < 10; k++) if (attrs[n * 10 + k] > 0.5f) z = k;
    species_o[n] = z;
    atomicAdd(&zcount[z], 1);
}

// bucket starts rounded up to 16-node tiles
__global__ void k_zscan(const int* __restrict__ zcount, int* __restrict__ zcur,
                        int* __restrict__ zstart) {
    if (threadIdx.x == 0) {
        int run = 0;
        for (int z = 0; z < 10; z++) {
            zstart[z] = run;
            zcur[z] = run;
            run += (zcount[z] + 15) & ~15;
        }
        zstart[10] = run;
    }
}

__global__ void k_zperm(const int* __restrict__ species_o, int* __restrict__ zcur,
                        int* __restrict__ perm_n, int* __restrict__ inv_n, int N) {
    int n = blockIdx.x * 256 + threadIdx.x;
    if (n >= N) return;
    int pos = atomicAdd(&zcur[species_o[n]], 1);
    perm_n[pos] = n;
    inv_n[n] = pos;
}

// mark pad slots (perm_n=-1, species filled for tile uniformity), zero deg everywhere
__global__ void k_padmark(const int* __restrict__ zstart, const int* __restrict__ zcur,
                          int* __restrict__ perm_n, int* __restrict__ deg,
                          int* __restrict__ species_s, int Npad) {
    int p = blockIdx.x * 256 + threadIdx.x;
    if (p >= Npad) return;
    deg[p] = 0;
    if (p >= zstart[10]) {
        perm_n[p] = -1;
        species_s[p] = 9;
        return;
    }
    int z = 9;
    #pragma unroll
    for (int q = 0; q < 10; q++) {
        if (p < zstart[q + 1]) { z = q; break; }
    }
    if (p >= zcur[z]) {
        perm_n[p] = -1;
        species_s[p] = z;
    }
}

// ---------------- init state in SPECIES-SORTED (padded) node order ----------------
__global__ void k_init(const int* __restrict__ perm_n, const int* __restrict__ species_o,
                       const float* __restrict__ Wemb, int* __restrict__ species_s,
                       int* __restrict__ origid, float* __restrict__ s,
                       float* __restrict__ v, int Npad) {
    int p = blockIdx.x * 4 + (threadIdx.x >> 6);
    if (p >= Npad) return;
    int lane = threadIdx.x & 63;
    int n = perm_n[p];
    if (n < 0) {
        if (lane == 0) origid[p] = -1;
        s[(size_t)p * 64 + lane] = 0.0f;
        v[(size_t)p * 192 + lane] = 0.0f;
        v[(size_t)p * 192 + 64 + lane] = 0.0f;
        v[(size_t)p * 192 + 128 + lane] = 0.0f;
        return;
    }
    int z = species_o[n];
    if (lane == 0) { species_s[p] = z; origid[p] = n; }
    s[(size_t)p * 64 + lane] = Wemb[z * 64 + lane];
    v[(size_t)p * 192 + lane] = 0.0f;
    v[(size_t)p * 192 + 64 + lane] = 0.0f;
    v[(size_t)p * 192 + 128 + lane] = 0.0f;
}

// ---------------- counting sort of edges by (sorted) receiver ----------------
__global__ void k_hist(const int* __restrict__ ei, const int* __restrict__ inv_n,
                       int* __restrict__ deg, int E) {
    int e = blockIdx.x * 256 + threadIdx.x;
    if (e < E) atomicAdd(&deg[inv_n[ei[E + e]]], 1);
}

__global__ void k_scan(const int* __restrict__ deg, int* __restrict__ rowptr,
                       int* __restrict__ cursor, int N) {
    __shared__ int part[1024];
    int t = threadIdx.x;
    int chunk = (N + 1023) / 1024;
    int lo = t * chunk, hi = min(lo + chunk, N);
    int sum = 0;
    for (int i = lo; i < hi; i++) sum += deg[i];
    part[t] = sum;
    __syncthreads();
    for (int off = 1; off < 1024; off <<= 1) {
        int add = (t >= off) ? part[t - off] : 0;
        __syncthreads();
        part[t] += add;
        __syncthreads();
    }
    int run = (t > 0) ? part[t - 1] : 0;
    for (int i = lo; i < hi; i++) { rowptr[i] = run; cursor[i] = run; run += deg[i]; }
    if (t == 1023) rowptr[N] = part[1023];
}

__global__ void k_eperm(const int* __restrict__ ei, const int* __restrict__ inv_n,
                        int* __restrict__ cursor, int* __restrict__ perm, int E) {
    int e = blockIdx.x * 256 + threadIdx.x;
    if (e < E) {
        int r = inv_n[ei[E + e]];
        int pos = atomicAdd(&cursor[r], 1);
        perm[pos] = e;
    }
}

// ---------------- geometry + radial basis; ef EDGE-MAJOR fp16; pads -> zero ----------
__global__ void k_geom(const int* __restrict__ ei, const int* __restrict__ perm,
                       const int* __restrict__ inv_n, const float* __restrict__ pos,
                       const float* __restrict__ shifts, float4* __restrict__ geo,
                       _Float16* __restrict__ efh, int* __restrict__ snd_s,
                       int* __restrict__ rcv_s, int E, int Epad, int padnode) {
    int j = blockIdx.x * 256 + threadIdx.x;
    if (j >= Epad) return;
    if (j >= E) {
        // pad edge: zero ef (=> exactly zero messages), sender/receiver = pad node
        geo[j] = make_float4(0.0f, 0.0f, 0.0f, 0.0f);
        snd_s[j] = padnode;
        rcv_s[j] = padnode;
        half8 z8;
        #pragma unroll
        for (int k = 0; k < 8; k++) z8[k] = (_Float16)0.0f;
        *(half8*)(efh + (size_t)j * 8) = z8;
        return;
    }
    int e = perm[j];
    int snd = ei[e], rcv = ei[E + e];
    float dx = pos[rcv * 3 + 0] - pos[snd * 3 + 0] + shifts[e * 3 + 0];
    float dy = pos[rcv * 3 + 1] - pos[snd * 3 + 1] + shifts[e * 3 + 1];
    float dz = pos[rcv * 3 + 2] - pos[snd * 3 + 2] + shifts[e * 3 + 2];
    float r = sqrtf(dx * dx + dy * dy + dz * dz);
    float rin = 1.0f / (r + 1e-9f);
    const float SQ3 = 1.7320508075688772f;
    geo[j] = make_float4(SQ3 * dx * rin, SQ3 * dy * rin, SQ3 * dz * rin, 0.0f);
    snd_s[j] = inv_n[snd];
    rcv_s[j] = inv_n[rcv];
    float u = r * 0.2f;
    float env = 0.0f;
    if (u < 1.0f) {
        float u2 = u * u;
        float u6 = u2 * u2 * u2;
        env = 1.0f - 28.0f * u6 + 48.0f * u6 * u - 21.0f * u6 * u2;
    }
    const float PIF = 3.14159265358979f;
    float x = PIF * u;
    float sp = __sinf(x), cp = __cosf(x);
    float coef = 0.6324555320336759f * rin * env;
    float sm1 = 0.0f, scur = sp, twoc = 2.0f * cp;
    half8 e8;
    #pragma unroll
    for (int k = 0; k < 8; k++) {
        e8[k] = (_Float16)(coef * scur);
        float nxt = twoc * scur - sm1;
        sm1 = scur; scur = nxt;
    }
    *(half8*)(efh + (size_t)j * 8) = e8;
}

// -------- weight prep (edge MLP): RW1/RW2/RW3 -> fp16 B-frag (16x16x32 MFMA) --------
// B3f is PRESCALED: group 0,2,3 (w00,w011,w101) * 1/32; group 1 (w110) * 1/(32*sqrt3);
// group 4 (w111) * 1/(32*sqrt2). Message epilogue then needs no constant multiplies.
__global__ void k_wprep(const float* __restrict__ RW1, const float* __restrict__ RW2,
                        const float* __restrict__ RW3, _Float16* __restrict__ B1f,
                        _Float16* __restrict__ B2f, _Float16* __restrict__ B3f) {
    int lane = threadIdx.x;
    int t = blockIdx.x;
    int layer = t / 52;
    int tt = t % 52;
    int quad = lane >> 4, colx = lane & 15;
    if (tt < 4) {
        int nt = tt;
        const float* W = RW1 + (size_t)layer * 512;
        _Float16* dst = B1f + (size_t)layer * 2048 + ((size_t)nt * 64 + lane) * 8;
        #pragma unroll
        for (int j = 0; j < 8; j++) {
            int k = quad * 8 + j, n = nt * 16 + colx;
            dst[j] = (k < 8) ? (_Float16)W[k * 64 + n] : (_Float16)0.0f;
        }
    } else if (tt < 12) {
        int u = tt - 4;
        int kt = u >> 2, nt = u & 3;
        const float* W = RW2 + (size_t)layer * 4096;
        _Float16* dst = B2f + (size_t)layer * 4096 + (((size_t)kt * 4 + nt) * 64 + lane) * 8;
        #pragma unroll
        for (int j = 0; j < 8; j++) {
            int k = kt * 32 + quad * 8 + j, n = nt * 16 + colx;
            dst[j] = (_Float16)W[k * 64 + n];
        }
    } else {
        int u = tt - 12;
        int kt = u / 20, nt = u % 20;
        const float* W = RW3 + (size_t)layer * 20480;
        _Float16* dst = B3f + (size_t)layer * 20480 + (((size_t)kt * 20 + nt) * 64 + lane) * 8;
        const float inv32 = 1.0f / 32.0f;
        const float is3 = 0.5773502691896258f;
        const float is2 = 0.7071067811865476f;
        #pragma unroll
        for (int j = 0; j < 8; j++) {
            int k = kt * 32 + quad * 8 + j, n = nt * 16 + colx;
            int grp = n >> 6;
            float scale = inv32 * (grp == 1 ? is3 : (grp == 4 ? is2 : 1.0f));
            dst[j] = (_Float16)(W[k * 320 + n] * scale);
        }
    }
}

// -------- weight prep (node mats): 64x64 fp32 -> B-frag fp16. 26 mats per layer -----
__global__ void k_wprep_node(const float* __restrict__ Wup_s, const float* __restrict__ Wup_v,
                             const float* __restrict__ Wout_s, const float* __restrict__ Wout_v,
                             const float* __restrict__ Wprod_s, const float* __restrict__ Wprod_v,
                             const float* __restrict__ Wsc_s, const float* __restrict__ Wsc_v,
                             _Float16* __restrict__ Bmats) {
    int mid = blockIdx.x;
    int layer = mid / 26, m = mid % 26;
    const float* src;
    if (m == 0)      src = Wup_s  + (size_t)layer * 4096;
    else if (m == 1) src = Wup_v  + (size_t)layer * 4096;
    else if (m == 2) src = Wout_s + (size_t)layer * 4096;
    else if (m == 3) src = Wout_v + (size_t)layer * 4096;
    else if (m == 4) src = Wprod_s + (size_t)layer * 4096;
    else if (m == 5) src = Wprod_v + (size_t)layer * 4096;
    else if (m < 16) src = Wsc_s + (size_t)layer * 40960 + (size_t)(m - 6) * 4096;
    else             src = Wsc_v + (size_t)layer * 40960 + (size_t)(m - 16) * 4096;
    _Float16* dst = Bmats + (size_t)mid * 4096;
    int lane = threadIdx.x, quad = lane >> 4, colx = lane & 15;
    for (int t = 0; t < 8; t++) {
        int kt = t >> 2, nt = t & 3;
        #pragma unroll
        for (int j = 0; j < 8; j++) {
            int k = kt * 32 + quad * 8 + j, n = nt * 16 + colx;
            dst[(size_t)t * 512 + lane * 8 + j] = (_Float16)src[k * 64 + n];
        }
    }
}

// helper: load A-frag (8 ch of one node) from planar fp32, fp16-convert
__device__ __forceinline__ half8 loadA(const float* __restrict__ base) {
    half8 a;
    float4 f0 = ((const float4*)base)[0];
    float4 f1 = ((const float4*)base)[1];
    a[0]=(_Float16)f0.x; a[1]=(_Float16)f0.y; a[2]=(_Float16)f0.z; a[3]=(_Float16)f0.w;
    a[4]=(_Float16)f1.x; a[5]=(_Float16)f1.y; a[6]=(_Float16)f1.z; a[7]=(_Float16)f1.w;
    return a;
}

// ---- node kernel A: up-projection (fp16 pack) + species skip (fp16 scph) + agg=0 ----
__global__ __launch_bounds__(256, 4)
void k_nodeA(const float* __restrict__ s, const float* __restrict__ v,
             const int* __restrict__ species,
             const _Float16* __restrict__ Bup_s, const _Float16* __restrict__ Bup_v,
             const _Float16* __restrict__ Bsc_s, const _Float16* __restrict__ Bsc_v,
             float2* __restrict__ packh, float2* __restrict__ scph,
             float* __restrict__ agg0, float* __restrict__ agg1, int Npad) {
    const int tid = threadIdx.x;
    const int lane = tid & 63, wave = tid >> 6;
    const int quad = lane >> 4, col = lane & 15;
    const int n0 = blockIdx.x * 64 + wave * 16;
    if (n0 >= Npad) return;

    half8 as[2], av0[2], av1[2], av2[2];
    int node = n0 + col;
    const float* sp = s + (size_t)node * 64;
    const float* vp = v + (size_t)node * 192;
    #pragma unroll
    for (int kt = 0; kt < 2; kt++) {
        int kb = kt * 32 + quad * 8;
        as[kt]  = loadA(sp + kb);
        av0[kt] = loadA(vp + kb);
        av1[kt] = loadA(vp + 64 + kb);
        av2[kt] = loadA(vp + 128 + kb);
    }

    const int z = species[n0];
    const _Float16* Bs = Bsc_s + (size_t)z * 4096;
    const _Float16* Bv = Bsc_v + (size_t)z * 4096;

    #pragma unroll
    for (int nt = 0; nt < 4; nt++) {
        floatx4 cs = {0,0,0,0}, c0 = {0,0,0,0}, c1 = {0,0,0,0}, c2 = {0,0,0,0};
        floatx4 ds = {0,0,0,0}, d0 = {0,0,0,0}, d1 = {0,0,0,0}, d2 = {0,0,0,0};
        #pragma unroll
        for (int kt = 0; kt < 2; kt++) {
            half8 bs = *(const half8*)(Bup_s + (((size_t)kt * 4 + nt) * 64 + lane) * 8);
            half8 bv = *(const half8*)(Bup_v + (((size_t)kt * 4 + nt) * 64 + lane) * 8);
            half8 es = *(const half8*)(Bs + (((size_t)kt * 4 + nt) * 64 + lane) * 8);
            half8 ev = *(const half8*)(Bv + (((size_t)kt * 4 + nt) * 64 + lane) * 8);
            cs = __builtin_amdgcn_mfma_f32_16x16x32_f16(as[kt],  bs, cs, 0, 0, 0);
            c0 = __builtin_amdgcn_mfma_f32_16x16x32_f16(av0[kt], bv, c0, 0, 0, 0);
            c1 = __builtin_amdgcn_mfma_f32_16x16x32_f16(av1[kt], bv, c1, 0, 0, 0);
            c2 = __builtin_amdgcn_mfma_f32_16x16x32_f16(av2[kt], bv, c2, 0, 0, 0);
            ds = __builtin_amdgcn_mfma_f32_16x16x32_f16(as[kt],  es, ds, 0, 0, 0);
            d0 = __builtin_amdgcn_mfma_f32_16x16x32_f16(av0[kt], ev, d0, 0, 0, 0);
            d1 = __builtin_amdgcn_mfma_f32_16x16x32_f16(av1[kt], ev, d1, 0, 0, 0);
            d2 = __builtin_amdgcn_mfma_f32_16x16x32_f16(av2[kt], ev, d2, 0, 0, 0);
        }
        int ch = nt * 16 + col;
        #pragma unroll
        for (int r = 0; r < 4; r++) {
            int n = n0 + quad * 4 + r;
            F2H u1, u2, w1, w2;
            u1.h[0] = (_Float16)cs[r]; u1.h[1] = (_Float16)c0[r];
            u2.h[0] = (_Float16)c1[r]; u2.h[1] = (_Float16)c2[r];
            w1.h[0] = (_Float16)ds[r]; w1.h[1] = (_Float16)d0[r];
            w2.h[0] = (_Float16)d1[r]; w2.h[1] = (_Float16)d2[r];
            packh[(size_t)n * 64 + ch] = make_float2(u1.f, u2.f);
            scph[(size_t)n * 64 + ch]  = make_float2(w1.f, w2.f);
            agg0[(size_t)n * 64 + ch] = 0.0f;
            agg1[(size_t)n * 192 + ch] = 0.0f;
            agg1[(size_t)n * 192 + 64 + ch] = 0.0f;
            agg1[(size_t)n * 192 + 128 + ch] = 0.0f;
        }
    }
}

// ---- message kernel: branch-free MFMA edge-MLP + LDS tile + wave-uniform reduction --
// Edges padded to x64 (pad: ef=0 => zero msgs, snd=rcv=padnode). B3f prescaled.
#define ROWP 72
#define MROW 66
__global__ __launch_bounds__(256, 4)
void k_msg(const _Float16* __restrict__ efh, const float4* __restrict__ geo,
           const int* __restrict__ snd_s, const int* __restrict__ rcv_s,
           const float2* __restrict__ packh,
           const _Float16* __restrict__ B1f, const _Float16* __restrict__ B2f,
           const _Float16* __restrict__ B3f,
           float* __restrict__ agg0, float* __restrict__ agg1) {
    __shared__ float2 mt[64 * MROW];             // 33792 B; a2/a3 overlay below
    _Float16* a2 = (_Float16*)mt;                // 9216 B
    _Float16* a3 = (_Float16*)mt + 4608;         // 9216 B
    const int tid = threadIdx.x;
    const int lane = tid & 63;
    const int wave = tid >> 6;
    const int quad = lane >> 4;
    const int col = lane & 15;
    const int j0 = blockIdx.x * 64 + wave * 16;

    _Float16* a2w = a2 + wave * 16 * ROWP;
    _Float16* a3w = a3 + wave * 16 * ROWP;

    // ---- stage 1: h1 = silu(ef @ RW1); all quads load (B1f rows k>=8 are zero) ----
    half8 aef = *(const half8*)(efh + (size_t)(j0 + col) * 8);
    {
        floatx4 c1[4];
        #pragma unroll
        for (int nt = 0; nt < 4; nt++) {
            c1[nt] = (floatx4){0.0f, 0.0f, 0.0f, 0.0f};
            half8 b = *(const half8*)(B1f + ((size_t)nt * 64 + lane) * 8);
            c1[nt] = __builtin_amdgcn_mfma_f32_16x16x32_f16(aef, b, c1[nt], 0, 0, 0);
        }
        #pragma unroll
        for (int nt = 0; nt < 4; nt++)
            #pragma unroll
            for (int r = 0; r < 4; r++)
                a2w[(quad * 4 + r) * ROWP + nt * 16 + col] = (_Float16)siluf(c1[nt][r]);
    }
    __syncthreads();

    // ---- stage 2: h2 = silu(h1 @ RW2) ----
    {
        half8 af0 = *(const half8*)&a2w[col * ROWP + quad * 8];
        half8 af1 = *(const half8*)&a2w[col * ROWP + 32 + quad * 8];
        floatx4 c2[4];
        #pragma unroll
        for (int nt = 0; nt < 4; nt++) {
            c2[nt] = (floatx4){0.0f, 0.0f, 0.0f, 0.0f};
            half8 b0 = *(const half8*)(B2f + (((size_t)0 * 4 + nt) * 64 + lane) * 8);
            half8 b1 = *(const half8*)(B2f + (((size_t)1 * 4 + nt) * 64 + lane) * 8);
            c2[nt] = __builtin_amdgcn_mfma_f32_16x16x32_f16(af0, b0, c2[nt], 0, 0, 0);
            c2[nt] = __builtin_amdgcn_mfma_f32_16x16x32_f16(af1, b1, c2[nt], 0, 0, 0);
        }
        #pragma unroll
        for (int nt = 0; nt < 4; nt++)
            #pragma unroll
            for (int r = 0; r < 4; r++)
                a3w[(quad * 4 + r) * ROWP + nt * 16 + col] = (_Float16)siluf(c2[nt][r]);
    }
    __syncthreads();

    half8 a3f0 = *(const half8*)&a3w[col * ROWP + quad * 8];
    half8 a3f1 = *(const half8*)&a3w[col * ROWP + 32 + quad * 8];
    __syncthreads();   // all waves hold a3 in regs before mt overlays the buffer

    // hoisted per-edge gathers (4 edges handled by this lane's quad rows)
    int sndr[4];
    float4 gr[4];
    #pragma unroll
    for (int r = 0; r < 4; r++) {
        int jj = j0 + quad * 4 + r;
        sndr[r] = snd_s[jj];
        gr[r] = geo[jj];
    }

    // ---- stage 3: w = h2 @ RW3 per 16-ch block; messages -> LDS tile ----
    for (int cb = 0; cb < 4; cb++) {
        floatx4 acc[5];
        #pragma unroll
        for (int q = 0; q < 5; q++) {
            acc[q] = (floatx4){0.0f, 0.0f, 0.0f, 0.0f};
            int nt = q * 4 + cb;
            half8 b0 = *(const half8*)(B3f + (((size_t)0 * 20 + nt) * 64 + lane) * 8);
            half8 b1 = *(const half8*)(B3f + (((size_t)1 * 20 + nt) * 64 + lane) * 8);
            acc[q] = __builtin_amdgcn_mfma_f32_16x16x32_f16(a3f0, b0, acc[q], 0, 0, 0);
            acc[q] = __builtin_amdgcn_mfma_f32_16x16x32_f16(a3f1, b1, acc[q], 0, 0, 0);
        }
        const int c = cb * 16 + col;
        #pragma unroll
        for (int r = 0; r < 4; r++) {
            int m = quad * 4 + r;
            float4 g = gr[r];
            float2 pp = packh[(size_t)sndr[r] * 64 + c];
            F2H u1, u2; u1.f = pp.x; u2.f = pp.y;
            float pvx = (float)u1.h[0], pvy = (float)u1.h[1];
            float pvz = (float)u2.h[0], pvw = (float)u2.h[1];
            float w00 = acc[0][r], w110 = acc[1][r], w011 = acc[2][r];
            float w101 = acc[3][r], w111 = acc[4][r];
            float dvy = pvy * g.x + pvz * g.y + pvw * g.z;
            float m0 = w00 * pvx + w110 * dvy;               // scales folded into B3f
            float cxv = pvz * g.z - pvw * g.y;
            float cyv = pvw * g.x - pvy * g.z;
            float czv = pvy * g.y - pvz * g.x;
            float wps = w011 * pvx;
            float m1x = wps * g.x + w101 * pvy + w111 * cxv;
            float m1y = wps * g.y + w101 * pvz + w111 * cyv;
            float m1z = wps * g.z + w101 * pvw + w111 * czv;
            F2H o1, o2;
            o1.h[0] = (_Float16)m0;  o1.h[1] = (_Float16)m1x;
            o2.h[0] = (_Float16)m1y; o2.h[1] = (_Float16)m1z;
            mt[(wave * 16 + m) * MROW + c] = make_float2(o1.f, o2.f);
        }
    }
    // no barrier: each wave reads only rows it wrote

    // ---- reduction: thread = (channel, wave-segment); wave-uniform run scan ----
    {
        const int c = lane;
        const int jb = j0;
        float a0 = 0.0f, a1 = 0.0f, a2v = 0.0f, a3v = 0.0f;
        int prev = -1;
        #pragma unroll 4
        for (int i = 0; i < 16; i++) {
            int rr = rcv_s[jb + i];      // wave-uniform scalar load
            float2 mv = mt[(wave * 16 + i) * MROW + c];
            F2H u1, u2; u1.f = mv.x; u2.f = mv.y;
            float m0 = (float)u1.h[0], m1 = (float)u1.h[1];
            float m2 = (float)u2.h[0], m3 = (float)u2.h[1];
            if (rr != prev) {            // wave-uniform branch
                if (prev >= 0) {
                    atomicAdd(&agg0[(size_t)prev * 64 + c], a0);
                    atomicAdd(&agg1[(size_t)prev * 192 + c], a1);
                    atomicAdd(&agg1[(size_t)prev * 192 + 64 + c], a2v);
                    atomicAdd(&agg1[(size_t)prev * 192 + 128 + c], a3v);
                }
                a0 = m0; a1 = m1; a2v = m2; a3v = m3;
                prev = rr;
            } else {
                a0 += m0; a1 += m1; a2v += m2; a3v += m3;
            }
        }
        if (prev >= 0) {
            atomicAdd(&agg0[(size_t)prev * 64 + c], a0);
            atomicAdd(&agg1[(size_t)prev * 192 + c], a1);
            atomicAdd(&agg1[(size_t)prev * 192 + 64 + c], a2v);
            atomicAdd(&agg1[(size_t)prev * 192 + 128 + c], a3v);
        }
    }
}

// ---- node kernel B: Wout MFMA -> P0/P1 epilogue -> LDS transpose -> Wprod MFMA -----
#define ROWPB 72
__global__ __launch_bounds__(256, 4)
void k_nodeB(const float* __restrict__ agg0, const float* __restrict__ agg1,
             const int* __restrict__ species, const int* __restrict__ origid,
             const _Float16* __restrict__ Bout_s, const _Float16* __restrict__ Bout_v,
             const _Float16* __restrict__ Bprod_s, const _Float16* __restrict__ Bprod_v,
             const float* __restrict__ P0l, const float* __restrict__ P1l,
             const float2* __restrict__ scph, float* __restrict__ s,
             float* __restrict__ v, float* __restrict__ out,
             int Npad, int layer, int Ltot) {
    __shared__ _Float16 lds[4 * 4 * 16 * ROWPB];
    const int tid = threadIdx.x;
    const int lane = tid & 63, wave = tid >> 6;
    const int quad = lane >> 4, col = lane & 15;
    const int n0 = blockIdx.x * 64 + wave * 16;
    if (n0 >= Npad) return;
    _Float16* lw = lds + wave * 4 * 16 * ROWPB;

    const int z = species[n0];
    {
        half8 as[2], av0[2], av1[2], av2[2];
        int node = n0 + col;
        const float* ap = agg0 + (size_t)node * 64;
        const float* vp = agg1 + (size_t)node * 192;
        #pragma unroll
        for (int kt = 0; kt < 2; kt++) {
            int kb = kt * 32 + quad * 8;
            as[kt]  = loadA(ap + kb);
            av0[kt] = loadA(vp + kb);
            av1[kt] = loadA(vp + 64 + kb);
            av2[kt] = loadA(vp + 128 + kb);
        }
        #pragma unroll
        for (int nt = 0; nt < 4; nt++) {
            floatx4 cs = {0,0,0,0}, c0 = {0,0,0,0}, c1 = {0,0,0,0}, c2 = {0,0,0,0};
            #pragma unroll
            for (int kt = 0; kt < 2; kt++) {
                half8 bs = *(const half8*)(Bout_s + (((size_t)kt * 4 + nt) * 64 + lane) * 8);
                half8 bv = *(const half8*)(Bout_v + (((size_t)kt * 4 + nt) * 64 + lane) * 8);
                cs = __builtin_amdgcn_mfma_f32_16x16x32_f16(as[kt],  bs, cs, 0, 0, 0);
                c0 = __builtin_amdgcn_mfma_f32_16x16x32_f16(av0[kt], bv, c0, 0, 0, 0);
                c1 = __builtin_amdgcn_mfma_f32_16x16x32_f16(av1[kt], bv, c1, 0, 0, 0);
                c2 = __builtin_amdgcn_mfma_f32_16x16x32_f16(av2[kt], bv, c2, 0, 0, 0);
            }
            int ch = nt * 16 + col;
            const float* p = P0l + ((size_t)z * 64 + ch) * 3;
            const float* q = P1l + ((size_t)z * 64 + ch) * 2;
            float p0 = p[0], p1 = p[1], p2 = p[2];
            float q0 = q[0], q1 = q[1];
            #pragma unroll
            for (int r = 0; r < 4; r++) {
                int nl = quad * 4 + r;
                float msv = cs[r];
                float m0 = c0[r], m1 = c1[r], m2 = c2[r];
                float ps = p0 * msv + p1 * msv * msv + p2 * (m0 * m0 + m1 * m1 + m2 * m2);
                float qq = q0 + q1 * msv;
                lw[0 * 16 * ROWPB + nl * ROWPB + ch] = (_Float16)ps;
                lw[1 * 16 * ROWPB + nl * ROWPB + ch] = (_Float16)(qq * m0);
                lw[2 * 16 * ROWPB + nl * ROWPB + ch] = (_Float16)(qq * m1);
                lw[3 * 16 * ROWPB + nl * ROWPB + ch] = (_Float16)(qq * m2);
            }
        }
    }
    __syncthreads();
    {
        half8 as[2], av0[2], av1[2], av2[2];
        #pragma unroll
        for (int kt = 0; kt < 2; kt++) {
            int kb = kt * 32 + quad * 8;
            as[kt]  = *(const half8*)&lw[0 * 16 * ROWPB + col * ROWPB + kb];
            av0[kt] = *(const half8*)&lw[1 * 16 * ROWPB + col * ROWPB + kb];
            av1[kt] = *(const half8*)&lw[2 * 16 * ROWPB + col * ROWPB + kb];
            av2[kt] = *(const half8*)&lw[3 * 16 * ROWPB + col * ROWPB + kb];
        }
        int og[4];
        #pragma unroll
        for (int r = 0; r < 4; r++) og[r] = origid[n0 + quad * 4 + r];
        #pragma unroll
        for (int nt = 0; nt < 4; nt++) {
            floatx4 cs = {0,0,0,0}, c0 = {0,0,0,0}, c1 = {0,0,0,0}, c2 = {0,0,0,0};
            #pragma unroll
            for (int kt = 0; kt < 2; kt++) {
                half8 bs = *(const half8*)(Bprod_s + (((size_t)kt * 4 + nt) * 64 + lane) * 8);
                half8 bv = *(const half8*)(Bprod_v + (((size_t)kt * 4 + nt) * 64 + lane) * 8);
                cs = __builtin_amdgcn_mfma_f32_16x16x32_f16(as[kt],  bs, cs, 0, 0, 0);
                c0 = __builtin_amdgcn_mfma_f32_16x16x32_f16(av0[kt], bv, c0, 0, 0, 0);
                c1 = __builtin_amdgcn_mfma_f32_16x16x32_f16(av1[kt], bv, c1, 0, 0, 0);
                c2 = __builtin_amdgcn_mfma_f32_16x16x32_f16(av2[kt], bv, c2, 0, 0, 0);
            }
            int ch = nt * 16 + col;
            #pragma unroll
            for (int r = 0; r < 4; r++) {
                int n = n0 + quad * 4 + r;
                float2 scv = scph[(size_t)n * 64 + ch];
                F2H u1, u2; u1.f = scv.x; u2.f = scv.y;
                float sval = cs[r] + (float)u1.h[0];
                s[(size_t)n * 64 + ch] = sval;
                v[(size_t)n * 192 + ch] = c0[r] + (float)u1.h[1];
                v[(size_t)n * 192 + 64 + ch] = c1[r] + (float)u2.h[0];
                v[(size_t)n * 192 + 128 + ch] = c2[r] + (float)u2.h[1];
                if (og[r] >= 0)
                    out[(size_t)og[r] * (Ltot * 64) + layer * 64 + ch] = sval;
            }
        }
    }
}

extern "C" void kernel_launch(void* const* d_in, const int* in_sizes, int n_in,
                              void* d_out, int out_size, void* d_ws, size_t ws_size,
                              hipStream_t stream) {
    const float* node_attrs = (const float*)d_in[0];
    const float* atom_pos   = (const float*)d_in[1];
    const float* shifts     = (const float*)d_in[2];
    const float* W_embed    = (const float*)d_in[3];
    const float* Wup_s      = (const float*)d_in[4];
    const float* Wup_v      = (const float*)d_in[5];
    const float* RW1        = (const float*)d_in[6];
    const float* RW2        = (const float*)d_in[7];
    const float* RW3        = (const float*)d_in[8];
    const float* Wout_s     = (const float*)d_in[9];
    const float* Wout_v     = (const float*)d_in[10];
    const float* Wsc_s      = (const float*)d_in[11];
    const float* Wsc_v      = (const float*)d_in[12];
    const float* P0         = (const float*)d_in[13];
    const float* P1         = (const float*)d_in[14];
    const float* Wprod_s    = (const float*)d_in[15];
    const float* Wprod_v    = (const float*)d_in[16];
    const int*   ei         = (const int*)d_in[17];

    const int N = in_sizes[0] / 10;
    const int E = in_sizes[17] / 2;
    const int L = in_sizes[4] / 4096;
    const int Npad = ((N + 160) + 63) / 64 * 64;   // species-padded, 64-aligned
    const int Epad = (E + 63) / 64 * 64;           // edge-padded to block size
    float* out = (float*)d_out;

    char* wsb = (char*)d_ws;
    size_t off = 0;
    auto alloci = [&](size_t n) {
        int* p = (int*)(wsb + off);
        off = (off + n * 4 + 255) / 256 * 256;
        return p;
    };
    auto allocf = [&](size_t n) {
        float* p = (float*)(wsb + off);
        off = (off + n * 4 + 255) / 256 * 256;
        return p;
    };
    auto alloch = [&](size_t n) {
        _Float16* p = (_Float16*)(wsb + off);
        off = (off + n * 2 + 255) / 256 * 256;
        return p;
    };
    int* species_o = alloci(N);
    int* species_s = alloci(Npad);
    int* zcount    = alloci(16);
    int* zcur      = alloci(16);
    int* zstart    = alloci(16);
    int* perm_n    = alloci(Npad);
    int* inv_n     = alloci(N);
    int* origid    = alloci(Npad);
    int* deg       = alloci(Npad);
    int* rowptr    = alloci(Npad + 1);
    int* cursor    = alloci(Npad);
    int* perm      = alloci(E);
    int* snd_s     = alloci(Epad);
    int* rcv_s     = alloci(Epad);
    float* s     = allocf((size_t)Npad * 64);
    float* v     = allocf((size_t)Npad * 192);
    float* agg0  = allocf((size_t)Npad * 64);
    float* agg1  = allocf((size_t)Npad * 192);
    float* geo   = allocf((size_t)Epad * 4);
    _Float16* efh = alloch((size_t)Epad * 8);
    float* packh = allocf((size_t)Npad * 128);
    float* scph  = allocf((size_t)Npad * 128);
    _Float16* B1f   = alloch((size_t)L * 2048);
    _Float16* B2f   = alloch((size_t)L * 4096);
    _Float16* B3f   = alloch((size_t)L * 20480);
    _Float16* Bmats = alloch((size_t)L * 26 * 4096);
    (void)n_in; (void)out_size; (void)ws_size;

    const int NT = Npad / 64;
    const int NB = (N + 255) / 256;
    const int NPB = (Npad + 255) / 256;
    const int EB = (E + 255) / 256;
    const int EPB = (Epad + 255) / 256;
    const int ET64 = Epad / 64;

    hipMemsetAsync(zcount, 0, 16 * sizeof(int), stream);
    k_species<<<NB, 256, 0, stream>>>(node_attrs, species_o, zcount, N);
    k_zscan<<<1, 64, 0, stream>>>(zcount, zcur, zstart);
    k_zperm<<<NB, 256, 0, stream>>>(species_o, zcur, perm_n, inv_n, N);
    k_padmark<<<NPB, 256, 0, stream>>>(zstart, zcur, perm_n, deg, species_s, Npad);
    k_init<<<(Npad + 3) / 4, 256, 0, stream>>>(perm_n, species_o, W_embed, species_s,
                                               origid, s, v, Npad);
    k_hist<<<EB, 256, 0, stream>>>(ei, inv_n, deg, E);
    k_scan<<<1, 1024, 0, stream>>>(deg, rowptr, cursor, Npad);
    k_eperm<<<EB, 256, 0, stream>>>(ei, inv_n, cursor, perm, E);
    k_geom<<<EPB, 256, 0, stream>>>(ei, perm, inv_n, atom_pos, shifts,
                                    (float4*)geo, efh, snd_s, rcv_s, E, Epad, Npad - 1);
    k_wprep<<<52 * L, 64, 0, stream>>>(RW1, RW2, RW3, B1f, B2f, B3f);
    k_wprep_node<<<26 * L, 64, 0, stream>>>(Wup_s, Wup_v, Wout_s, Wout_v,
                                            Wprod_s, Wprod_v, Wsc_s, Wsc_v, Bmats);

    for (int i = 0; i < L; i++) {
        const _Float16* Bl = Bmats + (size_t)i * 26 * 4096;
        k_nodeA<<<NT, 256, 0, stream>>>(s, v, species_s,
                                        Bl, Bl + 4096,
                                        Bl + 6 * 4096, Bl + 16 * 4096,
                                        (float2*)packh, (float2*)scph, agg0, agg1, Npad);
        k_msg<<<ET64, 256, 0, stream>>>(efh, (const float4*)geo, snd_s, rcv_s,
                                        (const float2*)packh,
                                        B1f + (size_t)i * 2048, B2f + (size_t)i * 4096,
                                        B3f + (size_t)i * 20480, agg0, agg1);
        k_nodeB<<<NT, 256, 0, stream>>>(agg0, agg1, species_s, origid,
                                        Bl + 2 * 4096, Bl + 3 * 4096,
                                        Bl + 4 * 4096, Bl + 5 * 4096,
                                        P0 + (size_t)i * 1920, P1 + (size_t)i * 1280,
                                        (const float2*)scph, s, v, out, Npad, i, L);
    }
}